// Round 4
// baseline (398.087 us; speedup 1.0000x reference)
//
#include <hip/hip_runtime.h>
#include <hip/hip_bf16.h>

// MLA prefill: B=2,S=2048,DIM=2048,NH=16,D_NOPE=128,D_ROPE=64,D_V=128,KV_RANK=512
// R9: R8 (32x32x16-fragment attention) with the P cross-half exchange done via
// __shfl_xor(...,32) instead of raw v_permlane32_swap_b32 asm. R8 failed
// correctness; the permlane asm was the only unverified mechanism (swap
// direction + uncovered VALU hazard wait-states on inline-asm permlane).
// Structure: 4 waves x 32 q per 128-q block; S^T = K.Q^T (q on col=lane&31);
// softmax reduce = one shfl_xor(32); P stays in registers; PV as O^T=V^T.P^T.
// 44KB LDS -> 2 blocks/CU with complementary causal pairing (id, id+256).
// GEMMs: global_load_lds width-16 (m97), unchanged.

typedef __bf16 bf16x8 __attribute__((ext_vector_type(8)));
typedef float  f32x4  __attribute__((ext_vector_type(4)));
typedef float  f32x16 __attribute__((ext_vector_type(16)));
typedef unsigned short us8 __attribute__((ext_vector_type(8)));
typedef unsigned short us4 __attribute__((ext_vector_type(4)));
typedef unsigned int   ui4 __attribute__((ext_vector_type(4)));

#define S_LEN   2048
#define BS_TOT  4096   // B*S
#define NH      16
#define DQK     192
#define DV      128
#define KV_RANK 512

__device__ inline unsigned short f2bf(float f) {
  __hip_bfloat16 h = __float2bfloat16(f);
  return *reinterpret_cast<unsigned short*>(&h);
}
__device__ inline unsigned int pack2bf(float a, float b) {
  return (unsigned int)f2bf(a) | ((unsigned int)f2bf(b) << 16);
}
__device__ inline void glds16(const void* g, void* l) {
  __builtin_amdgcn_global_load_lds(
      (const __attribute__((address_space(1))) unsigned int*)g,
      (__attribute__((address_space(3))) unsigned int*)l, 16, 0, 0);
}

// ---------------- f32 -> bf16 cast (with zero pad to npad) ----------------
__global__ void cast_f32_bf16_kernel(const float* __restrict__ src,
                                     __hip_bfloat16* __restrict__ dst,
                                     int n, int npad) {
  int tid = blockIdx.x * blockDim.x + threadIdx.x;
  int stride = gridDim.x * blockDim.x;
  for (int i = tid * 4; i < npad; i += stride * 4) {
    if (i < n) {
      f32x4 v = *(const f32x4*)(src + i);
      dst[i + 0] = __float2bfloat16(v.x);
      dst[i + 1] = __float2bfloat16(v.y);
      dst[i + 2] = __float2bfloat16(v.z);
      dst[i + 3] = __float2bfloat16(v.w);
    } else {
      dst[i + 0] = __float2bfloat16(0.f);
      dst[i + 1] = __float2bfloat16(0.f);
      dst[i + 2] = __float2bfloat16(0.f);
      dst[i + 3] = __float2bfloat16(0.f);
    }
  }
}

// ---------------- bf16 MFMA GEMM: C[M,N] = A[M,K] @ Bw[N,K]^T ----------------
// m97 structure: global_load_lds width-16 staging, 128x128 tile, BK=32.
// Bw must have >= ceil(N/128)*128 valid rows (zero-padded if needed).
template<int OUT_BF16>
__global__ __launch_bounds__(256) void gemm_bt(const __hip_bfloat16* __restrict__ A,
                                               const __hip_bfloat16* __restrict__ Bw,
                                               void* __restrict__ Cp,
                                               int M, int N, int K) {
  constexpr int BM = 128, BN = 128, BK = 32;
  __shared__ alignas(16) unsigned short As[BM * BK];
  __shared__ alignas(16) unsigned short Bs[BN * BK];
  const int tid  = threadIdx.x;
  const int m0   = blockIdx.y * BM, n0 = blockIdx.x * BN;
  const int w    = tid >> 6, lane = tid & 63;
  const int wm   = (w >> 1) * 64, wn = (w & 1) * 64;
  const int ml   = lane & 15, quad = lane >> 4;
  const int srow = w * 16 + (lane >> 2);   // staging row within 64-row half
  const int scol = (lane & 3) * 8;         // staging col (elems)

  f32x4 acc[4][4];
#pragma unroll
  for (int i = 0; i < 4; i++)
#pragma unroll
    for (int j = 0; j < 4; j++)
#pragma unroll
      for (int e = 0; e < 4; e++) acc[i][j][e] = 0.0f;

  const unsigned short* Ag = (const unsigned short*)A;
  const unsigned short* Bg = (const unsigned short*)Bw;
  const unsigned short* a0 = Ag + (size_t)(m0 + srow) * K + scol;
  const unsigned short* a1 = Ag + (size_t)(m0 + srow + 64) * K + scol;
  const unsigned short* b0 = Bg + (size_t)(n0 + srow) * K + scol;
  const unsigned short* b1 = Bg + (size_t)(n0 + srow + 64) * K + scol;
  unsigned short* lA0 = &As[(w * 16) * BK];        // wave-uniform LDS bases
  unsigned short* lA1 = &As[(64 + w * 16) * BK];
  unsigned short* lB0 = &Bs[(w * 16) * BK];
  unsigned short* lB1 = &Bs[(64 + w * 16) * BK];

  for (int k0 = 0; k0 < K; k0 += BK) {
    __syncthreads();
    glds16(a0 + k0, lA0);
    glds16(a1 + k0, lA1);
    glds16(b0 + k0, lB0);
    glds16(b1 + k0, lB1);
    __syncthreads();

    bf16x8 af[4], bfr[4];
#pragma unroll
    for (int mi = 0; mi < 4; mi++)
      af[mi] = *(const bf16x8*)&As[(wm + mi * 16 + ml) * BK + quad * 8];
#pragma unroll
    for (int ni = 0; ni < 4; ni++)
      bfr[ni] = *(const bf16x8*)&Bs[(wn + ni * 16 + ml) * BK + quad * 8];
#pragma unroll
    for (int mi = 0; mi < 4; mi++)
#pragma unroll
      for (int ni = 0; ni < 4; ni++)
        acc[mi][ni] = __builtin_amdgcn_mfma_f32_16x16x32_bf16(af[mi], bfr[ni],
                                                              acc[mi][ni], 0, 0, 0);
  }

#pragma unroll
  for (int mi = 0; mi < 4; mi++) {
#pragma unroll
    for (int ni = 0; ni < 4; ni++) {
      int col = n0 + wn + ni * 16 + ml;
      if (col < N) {
#pragma unroll
        for (int j = 0; j < 4; j++) {
          int row = m0 + wm + mi * 16 + quad * 4 + j;
          float v = acc[mi][ni][j];
          if (OUT_BF16)
            ((__hip_bfloat16*)Cp)[(size_t)row * N + col] = __float2bfloat16(v);
          else
            ((float*)Cp)[(size_t)row * N + col] = v;
        }
      }
    }
  }
}

// ---------------- RoPE on q_pe (in place, bf16 q [BS][NH*192]) ----------------
__global__ __launch_bounds__(256) void rope_q_kernel(__hip_bfloat16* __restrict__ q,
                                                     const float* __restrict__ freqs) {
  int si = blockIdx.x;
  int s  = si & (S_LEN - 1);
  int tid = threadIdx.x;
  for (int p = tid; p < NH * 32; p += 256) {
    int h = p >> 5, i = p & 31;
    size_t base = (size_t)si * (NH * DQK) + h * DQK + 128 + 2 * i;
    float c  = freqs[s * 64 + 2 * i];
    float sn = freqs[s * 64 + 2 * i + 1];
    float x0 = __bfloat162float(q[base]);
    float x1 = __bfloat162float(q[base + 1]);
    q[base]     = __float2bfloat16(x0 * c - x1 * sn);
    q[base + 1] = __float2bfloat16(x0 * sn + x1 * c);
  }
}

// -------- RMSNorm(kv latent) -> bf16, RoPE(k_pe) -> bf16 ---------------------
__global__ __launch_bounds__(256) void rms_rope_kv_kernel(
    const float* __restrict__ kva, const float* __restrict__ w,
    const float* __restrict__ freqs, __hip_bfloat16* __restrict__ latent,
    __hip_bfloat16* __restrict__ kpe_out) {
  int si = blockIdx.x;
  int tid = threadIdx.x;
  const float* row = kva + (size_t)si * 576;
  float v0 = row[tid], v1 = row[tid + 256];
  float ss = v0 * v0 + v1 * v1;
#pragma unroll
  for (int off = 1; off < 64; off <<= 1) ss += __shfl_xor(ss, off, 64);
  __shared__ float red[4];
  if ((tid & 63) == 0) red[tid >> 6] = ss;
  __syncthreads();
  float tot = red[0] + red[1] + red[2] + red[3];
  float r = rsqrtf(tot / 512.0f + 1e-6f);
  latent[(size_t)si * 512 + tid]       = __float2bfloat16(v0 * r * w[tid]);
  latent[(size_t)si * 512 + tid + 256] = __float2bfloat16(v1 * r * w[tid + 256]);
  if (tid < 32) {
    int s = si & (S_LEN - 1);
    float c  = freqs[s * 64 + 2 * tid];
    float sn = freqs[s * 64 + 2 * tid + 1];
    float x0 = row[512 + 2 * tid], x1 = row[512 + 2 * tid + 1];
    kpe_out[(size_t)si * 64 + 2 * tid]     = __float2bfloat16(x0 * c - x1 * sn);
    kpe_out[(size_t)si * 64 + 2 * tid + 1] = __float2bfloat16(x0 * sn + x1 * c);
  }
}

// ---------------- 32x32-fragment MFMA flash attention --------------------------
// grid: 512 linear blocks; 256 threads = 4 waves x 32 q rows each. K-tile 64.
// id -> (b,h,qt) with qt = id<256 ? e&15 : 15-(e&15) (complementary pairs on a
// CU; 2 blocks/CU at 44KB LDS). S^T = K.Q^T with 32x32x16 (q on col=lane&31);
// softmax reduce = one shfl_xor(32); P -> PV B-frag in registers via
// pack2bf + shfl_xor(32) cross-half exchange; PV as O^T = V^T.P^T.
__global__ __launch_bounds__(256, 2) void attn_mfma_kernel(
    const __hip_bfloat16* __restrict__ qb,    // [BS][NH*192]
    const __hip_bfloat16* __restrict__ kvup,  // [BS][NH*256] (nope|v per head)
    const __hip_bfloat16* __restrict__ kpe,   // [BS][64] bf16
    __hip_bfloat16* __restrict__ attn_out) {  // [BS][NH*128]
  constexpr int KS = 200;   // Ks row stride (bf16 elems), 400B: 16B-aligned rows
  constexpr int VS = 36;    // Vt2 row stride (dwords)
  __shared__ alignas(16) unsigned short Ks[64 * KS];    // 25600 B
  __shared__ alignas(16) unsigned int   Vt2[128 * VS];  // 18432 B

  const int id = blockIdx.x;
  const int b  = id >> 8;
  const int e  = id & 255;
  const int h  = e >> 4;
  const int qt = b ? (15 - (e & 15)) : (e & 15);

  const int tid = threadIdx.x, wave = tid >> 6, lane = tid & 63;
  const int l31 = lane & 31, hh = lane >> 5;
  const int qwb = qt * 128 + wave * 32;   // wave's q base
  const int qg  = qwb + l31;              // lane's q (col = lane&31)
  const float qs2 = 0.07216878364870322f * 1.4426950408889634f;  // scale*log2e

  // resident Q B-frags: col=l31 -> q row qg; d = s*16 + hh*8 + e
  bf16x8 Qf[12];
  {
    const unsigned short* qrow = (const unsigned short*)qb +
        (size_t)(b * S_LEN + qg) * (NH * DQK) + h * DQK;
#pragma unroll
    for (int s = 0; s < 12; s++)
      Qf[s] = *(const bf16x8*)(qrow + s * 16 + hh * 8);
  }

  const int m16 = tid & 15;           // V staging: d-chunk owner
  const int vq  = tid >> 4;           // V staging: 4-kpos group 0..15
  const int vkey = (m16 & 7) << 2;    // V write swizzle (row d>>3 = m16)
  const unsigned short* kvbase = (const unsigned short*)kvup;
  const unsigned short* kpbase = (const unsigned short*)kpe;

  float m_i = -1e30f, l_i = 0.0f;
  f32x16 O2[4];  // O^T: tile mt covers v = mt*32 + (r&3)+8*(r>>2)+4*hh, q = l31
#pragma unroll
  for (int mt = 0; mt < 4; mt++)
#pragma unroll
    for (int j = 0; j < 16; j++) O2[mt][j] = 0.0f;

  const int nkt = 2 * qt + 2;

  // ---- prefetch tile 0 into registers ----
  us8 Kpre[6], Vpre[4];
  {
#pragma unroll
    for (int it = 0; it < 6; it++) {
      int slot = tid + it * 256;
      int r = slot / 24, c = slot - r * 24;
      size_t grow = (size_t)(b * S_LEN + r);
      Kpre[it] = (c < 16)
          ? *(const us8*)(kvbase + grow * (NH * 256) + h * 256 + c * 8)
          : *(const us8*)(kpbase + grow * 64 + (c - 16) * 8);
    }
    const unsigned short* v0 = kvbase +
        (size_t)(b * S_LEN + vq * 4) * (NH * 256) + h * 256 + 128 + m16 * 8;
#pragma unroll
    for (int u = 0; u < 4; u++) Vpre[u] = *(const us8*)(v0 + u * (NH * 256));
  }

  for (int kt = 0; kt < nkt; kt++) {
    const int kb = kt * 64;
    __syncthreads();  // all waves done reading previous tile
#pragma unroll
    for (int it = 0; it < 6; it++) {
      int slot = tid + it * 256;
      int r = slot / 24, c = slot - r * 24;
      *(us8*)&Ks[r * KS + c * 8] = Kpre[it];
    }
#pragma unroll
    for (int z = 0; z < 8; z++) {
      int d = m16 * 8 + z;
      Vt2[d * VS + ((vq * 2 + 0) ^ vkey)] =
          (unsigned)(unsigned short)Vpre[0][z] |
          ((unsigned)(unsigned short)Vpre[1][z] << 16);
      Vt2[d * VS + ((vq * 2 + 1) ^ vkey)] =
          (unsigned)(unsigned short)Vpre[2][z] |
          ((unsigned)(unsigned short)Vpre[3][z] << 16);
    }
    __syncthreads();

    if (kt + 1 < nkt) {
      const int kb2 = kb + 64;
#pragma unroll
      for (int it = 0; it < 6; it++) {
        int slot = tid + it * 256;
        int r = slot / 24, c = slot - r * 24;
        size_t grow = (size_t)(b * S_LEN + kb2 + r);
        Kpre[it] = (c < 16)
            ? *(const us8*)(kvbase + grow * (NH * 256) + h * 256 + c * 8)
            : *(const us8*)(kpbase + grow * 64 + (c - 16) * 8);
      }
      const unsigned short* v0 = kvbase +
          (size_t)(b * S_LEN + kb2 + vq * 4) * (NH * 256) + h * 256 + 128 + m16 * 8;
#pragma unroll
      for (int u = 0; u < 4; u++) Vpre[u] = *(const us8*)(v0 + u * (NH * 256));
    }

    if (kb > qwb + 31) continue;  // per-wave causal skip

    // ---- S^T = K.Q^T (32x32x16): rows kpos, cols q=l31 ----
    f32x16 st2[2];
    __builtin_amdgcn_s_setprio(1);
#pragma unroll
    for (int mt = 0; mt < 2; mt++) {
      f32x16 acc;
#pragma unroll
      for (int j = 0; j < 16; j++) acc[j] = 0.0f;
#pragma unroll
      for (int s = 0; s < 12; s++) {
        bf16x8 kf = *(const bf16x8*)&Ks[(mt * 32 + l31) * KS + s * 16 + hh * 8];
        acc = __builtin_amdgcn_mfma_f32_32x32x16_bf16(kf, Qf[s], acc, 0, 0, 0);
      }
      st2[mt] = acc;
    }
    __builtin_amdgcn_s_setprio(0);

    // ---- online softmax (exp2 domain); lane owns q = qg ----
    // reg r of tile mt: kpos = kb + mt*32 + (r&3) + 8*(r>>2) + 4*hh
    float mloc = -1e30f;
    if (kb + 64 <= qwb) {  // tile fully below diagonal: no mask needed
#pragma unroll
      for (int mt = 0; mt < 2; mt++)
#pragma unroll
        for (int r = 0; r < 16; r++) {
          float s = st2[mt][r] * qs2;
          st2[mt][r] = s;
          mloc = fmaxf(mloc, s);
        }
    } else {
#pragma unroll
      for (int mt = 0; mt < 2; mt++)
#pragma unroll
        for (int r = 0; r < 16; r++) {
          int kpos = kb + mt * 32 + (r & 3) + 8 * (r >> 2) + 4 * hh;
          float s = st2[mt][r] * qs2;
          s = (kpos > qg) ? -1e30f : s;
          st2[mt][r] = s;
          mloc = fmaxf(mloc, s);
        }
    }
    mloc = fmaxf(mloc, __shfl_xor(mloc, 32, 64));
    float m_new = fmaxf(m_i, mloc);
    float alpha = exp2f(m_i - m_new);
    float psum = 0.0f;
#pragma unroll
    for (int mt = 0; mt < 2; mt++)
#pragma unroll
      for (int r = 0; r < 16; r++) {
        float p = exp2f(st2[mt][r] - m_new);
        st2[mt][r] = p;
        psum += p;
      }
    psum += __shfl_xor(psum, 32, 64);
    l_i = l_i * alpha + psum;
    m_i = m_new;

    // rescale O^T: q = l31 on all regs -> lane-local alpha
#pragma unroll
    for (int mt = 0; mt < 4; mt++)
#pragma unroll
      for (int j = 0; j < 16; j++) O2[mt][j] *= alpha;

    // ---- P -> PV B-frags in registers; cross-half exchange via shfl_xor(32) --
    // B-frag slice ss: lane needs P[q=qg][k-in-tile = ss*16 + hh*8 + {0..7}].
    // Own regs hold offsets (r&3)+8*(r>>2)+4*hh; partner lane^32 holds the
    // interleaved 4-groups. U0..U3 = packed own pairs; exchange 2 dwords.
    bf16x8 pf[4];
#pragma unroll
    for (int ss = 0; ss < 4; ss++) {
      const int pmt = ss >> 1, gg = ss & 1;
      unsigned int U0 = pack2bf(st2[pmt][gg * 8 + 0], st2[pmt][gg * 8 + 1]);
      unsigned int U1 = pack2bf(st2[pmt][gg * 8 + 2], st2[pmt][gg * 8 + 3]);
      unsigned int U2 = pack2bf(st2[pmt][gg * 8 + 4], st2[pmt][gg * 8 + 5]);
      unsigned int U3 = pack2bf(st2[pmt][gg * 8 + 6], st2[pmt][gg * 8 + 7]);
      unsigned int E0 = __shfl_xor(hh ? U0 : U2, 32, 64);
      unsigned int E1 = __shfl_xor(hh ? U1 : U3, 32, 64);
      ui4 pd;
      pd.x = hh ? E0 : U0;   // offsets gg*16 + hh*8 + (0,1)
      pd.y = hh ? E1 : U1;   //                      + (2,3)
      pd.z = hh ? U2 : E0;   //                      + (4,5)
      pd.w = hh ? U3 : E1;   //                      + (6,7)
      pf[ss] = __builtin_bit_cast(bf16x8, pd);
    }

    // ---- PV as O^T = V^T.P^T: A=V^T rows (v, kpos), B=P (q=l31, kpos) ----
    __builtin_amdgcn_s_setprio(1);
#pragma unroll
    for (int ss = 0; ss < 4; ss++) {
#pragma unroll
      for (int mt = 0; mt < 4; mt++) {
        int v = mt * 32 + l31;
        const unsigned int* vp =
            &Vt2[v * VS + ((ss * 8 + hh * 4) ^ (((v >> 3) & 7) << 2))];
        bf16x8 bv = *(const bf16x8*)vp;
        O2[mt] = __builtin_amdgcn_mfma_f32_32x32x16_bf16(bv, pf[ss], O2[mt], 0, 0, 0);
      }
    }
    __builtin_amdgcn_s_setprio(0);
  }

  // ---- epilogue: O^T reg r of mt = v = mt*32 + (r&3)+8*(r>>2)+4*hh, q = qg ----
  float invl = 1.0f / l_i;
  size_t orow = (size_t)(b * S_LEN + qg) * (NH * DV) + h * DV;
#pragma unroll
  for (int mt = 0; mt < 4; mt++) {
#pragma unroll
    for (int g = 0; g < 4; g++) {
      us4 pk;
#pragma unroll
      for (int j = 0; j < 4; j++) pk[j] = f2bf(O2[mt][g * 4 + j] * invl);
      *(us4*)((unsigned short*)attn_out + orow + mt * 32 + g * 8 + hh * 4) = pk;
    }
  }
}

// ---------------- launch ----------------
extern "C" void kernel_launch(void* const* d_in, const int* in_sizes, int n_in,
                              void* d_out, int out_size, void* d_ws, size_t ws_size,
                              hipStream_t stream) {
  const float* x     = (const float*)d_in[0];
  const float* freqs = (const float*)d_in[2];
  const float* wq    = (const float*)d_in[4];
  const float* wkva  = (const float*)d_in[5];
  const float* wkvb  = (const float*)d_in[6];
  const float* wo    = (const float*)d_in[7];
  const float* kvnw  = (const float*)d_in[8];
  float* out = (float*)d_out;

  char* ws = (char*)d_ws;
  size_t off = 0;
  auto alloc = [&](size_t bytes) {
    void* p = ws + off;
    off += (bytes + 255) & ~(size_t)255;
    return p;
  };
  __hip_bfloat16* x_bf    = (__hip_bfloat16*)alloc((size_t)BS_TOT * 2048 * 2);
  __hip_bfloat16* wq_bf   = (__hip_bfloat16*)alloc((size_t)3072 * 2048 * 2);
  __hip_bfloat16* wkva_bf = (__hip_bfloat16*)alloc((size_t)640 * 2048 * 2);  // padded
  __hip_bfloat16* wkvb_bf = (__hip_bfloat16*)alloc((size_t)4096 * 512 * 2);
  __hip_bfloat16* wo_bf   = (__hip_bfloat16*)alloc((size_t)2048 * 2048 * 2);
  __hip_bfloat16* q_bf    = (__hip_bfloat16*)alloc((size_t)BS_TOT * 3072 * 2);
  float*          kva     = (float*)alloc((size_t)BS_TOT * 576 * 4);
  __hip_bfloat16* latent  = (__hip_bfloat16*)alloc((size_t)BS_TOT * 512 * 2);
  __hip_bfloat16* kpe     = (__hip_bfloat16*)alloc((size_t)BS_TOT * 64 * 2);
  __hip_bfloat16* kvup    = (__hip_bfloat16*)alloc((size_t)BS_TOT * 4096 * 2);
  __hip_bfloat16* attn    = (__hip_bfloat16*)alloc((size_t)BS_TOT * 2048 * 2);

  cast_f32_bf16_kernel<<<2048, 256, 0, stream>>>(x, x_bf, BS_TOT * 2048,
                                                 BS_TOT * 2048);
  cast_f32_bf16_kernel<<<2048, 256, 0, stream>>>(wq, wq_bf, 3072 * 2048,
                                                 3072 * 2048);
  cast_f32_bf16_kernel<<<1024, 256, 0, stream>>>(wkva, wkva_bf, 576 * 2048,
                                                 640 * 2048);
  cast_f32_bf16_kernel<<<1024, 256, 0, stream>>>(wkvb, wkvb_bf, 4096 * 512,
                                                 4096 * 512);
  cast_f32_bf16_kernel<<<2048, 256, 0, stream>>>(wo, wo_bf, 2048 * 2048,
                                                 2048 * 2048);

  gemm_bt<1><<<dim3(3072 / 128, BS_TOT / 128), 256, 0, stream>>>(
      x_bf, wq_bf, q_bf, BS_TOT, 3072, 2048);
  rope_q_kernel<<<BS_TOT, 256, 0, stream>>>(q_bf, freqs);

  gemm_bt<0><<<dim3(5, BS_TOT / 128), 256, 0, stream>>>(
      x_bf, wkva_bf, kva, BS_TOT, 576, 2048);
  rms_rope_kv_kernel<<<BS_TOT, 256, 0, stream>>>(kva, kvnw, freqs, latent, kpe);

  gemm_bt<1><<<dim3(4096 / 128, BS_TOT / 128), 256, 0, stream>>>(
      latent, wkvb_bf, kvup, BS_TOT, 4096, 512);

  attn_mfma_kernel<<<dim3(512, 1, 1), 256, 0, stream>>>(
      q_bf, kvup, kpe, attn);

  gemm_bt<0><<<dim3(2048 / 128, BS_TOT / 128), 256, 0, stream>>>(
      attn, wo_bf, out, BS_TOT, 2048, 2048);
}

// Round 6
// 344.252 us; speedup vs baseline: 1.1564x; 1.1564x over previous
//
#include <hip/hip_runtime.h>
#include <hip/hip_bf16.h>

// MLA prefill: B=2,S=2048,DIM=2048,NH=16,D_NOPE=128,D_ROPE=64,D_V=128,KV_RANK=512
// R10 (resubmit; previous bench died with UnresponsiveContainer before running).
// Attention pipeline restructure (m214 geometry). R5-R9 all plateau at
// ~170us with nothing saturated -> the single-buffered 2-barrier-per-tile
// skeleton was the floor. Now: 256 q/block (8 waves x 32 q, grid 256; halves
// KV re-reads AND per-CU barrier count), double-buffered K/V LDS with ONE
// barrier per tile, async-STAGE split (issue global->reg loads before compute,
// vmcnt+LDS-write after). Inner math (32x32x16 QK/PV, in-reg P via shfl_xor,
// exp2 softmax, V swizzle) identical to verified R9; K staging identical to R5.
// GEMMs: global_load_lds width-16 (m97), unchanged.

typedef __bf16 bf16x8 __attribute__((ext_vector_type(8)));
typedef float  f32x4  __attribute__((ext_vector_type(4)));
typedef float  f32x16 __attribute__((ext_vector_type(16)));
typedef unsigned short us8 __attribute__((ext_vector_type(8)));
typedef unsigned short us4 __attribute__((ext_vector_type(4)));
typedef unsigned int   ui4 __attribute__((ext_vector_type(4)));

#define S_LEN   2048
#define BS_TOT  4096   // B*S
#define NH      16
#define DQK     192
#define DV      128
#define KV_RANK 512

__device__ inline unsigned short f2bf(float f) {
  __hip_bfloat16 h = __float2bfloat16(f);
  return *reinterpret_cast<unsigned short*>(&h);
}
__device__ inline unsigned int pack2bf(float a, float b) {
  return (unsigned int)f2bf(a) | ((unsigned int)f2bf(b) << 16);
}
__device__ inline void glds16(const void* g, void* l) {
  __builtin_amdgcn_global_load_lds(
      (const __attribute__((address_space(1))) unsigned int*)g,
      (__attribute__((address_space(3))) unsigned int*)l, 16, 0, 0);
}

// ---------------- f32 -> bf16 cast (with zero pad to npad) ----------------
__global__ void cast_f32_bf16_kernel(const float* __restrict__ src,
                                     __hip_bfloat16* __restrict__ dst,
                                     int n, int npad) {
  int tid = blockIdx.x * blockDim.x + threadIdx.x;
  int stride = gridDim.x * blockDim.x;
  for (int i = tid * 4; i < npad; i += stride * 4) {
    if (i < n) {
      f32x4 v = *(const f32x4*)(src + i);
      dst[i + 0] = __float2bfloat16(v.x);
      dst[i + 1] = __float2bfloat16(v.y);
      dst[i + 2] = __float2bfloat16(v.z);
      dst[i + 3] = __float2bfloat16(v.w);
    } else {
      dst[i + 0] = __float2bfloat16(0.f);
      dst[i + 1] = __float2bfloat16(0.f);
      dst[i + 2] = __float2bfloat16(0.f);
      dst[i + 3] = __float2bfloat16(0.f);
    }
  }
}

// ---------------- bf16 MFMA GEMM: C[M,N] = A[M,K] @ Bw[N,K]^T ----------------
template<int OUT_BF16>
__global__ __launch_bounds__(256) void gemm_bt(const __hip_bfloat16* __restrict__ A,
                                               const __hip_bfloat16* __restrict__ Bw,
                                               void* __restrict__ Cp,
                                               int M, int N, int K) {
  constexpr int BM = 128, BN = 128, BK = 32;
  __shared__ alignas(16) unsigned short As[BM * BK];
  __shared__ alignas(16) unsigned short Bs[BN * BK];
  const int tid  = threadIdx.x;
  const int m0   = blockIdx.y * BM, n0 = blockIdx.x * BN;
  const int w    = tid >> 6, lane = tid & 63;
  const int wm   = (w >> 1) * 64, wn = (w & 1) * 64;
  const int ml   = lane & 15, quad = lane >> 4;
  const int srow = w * 16 + (lane >> 2);   // staging row within 64-row half
  const int scol = (lane & 3) * 8;         // staging col (elems)

  f32x4 acc[4][4];
#pragma unroll
  for (int i = 0; i < 4; i++)
#pragma unroll
    for (int j = 0; j < 4; j++)
#pragma unroll
      for (int e = 0; e < 4; e++) acc[i][j][e] = 0.0f;

  const unsigned short* Ag = (const unsigned short*)A;
  const unsigned short* Bg = (const unsigned short*)Bw;
  const unsigned short* a0 = Ag + (size_t)(m0 + srow) * K + scol;
  const unsigned short* a1 = Ag + (size_t)(m0 + srow + 64) * K + scol;
  const unsigned short* b0 = Bg + (size_t)(n0 + srow) * K + scol;
  const unsigned short* b1 = Bg + (size_t)(n0 + srow + 64) * K + scol;
  unsigned short* lA0 = &As[(w * 16) * BK];        // wave-uniform LDS bases
  unsigned short* lA1 = &As[(64 + w * 16) * BK];
  unsigned short* lB0 = &Bs[(w * 16) * BK];
  unsigned short* lB1 = &Bs[(64 + w * 16) * BK];

  for (int k0 = 0; k0 < K; k0 += BK) {
    __syncthreads();
    glds16(a0 + k0, lA0);
    glds16(a1 + k0, lA1);
    glds16(b0 + k0, lB0);
    glds16(b1 + k0, lB1);
    __syncthreads();

    bf16x8 af[4], bfr[4];
#pragma unroll
    for (int mi = 0; mi < 4; mi++)
      af[mi] = *(const bf16x8*)&As[(wm + mi * 16 + ml) * BK + quad * 8];
#pragma unroll
    for (int ni = 0; ni < 4; ni++)
      bfr[ni] = *(const bf16x8*)&Bs[(wn + ni * 16 + ml) * BK + quad * 8];
#pragma unroll
    for (int mi = 0; mi < 4; mi++)
#pragma unroll
      for (int ni = 0; ni < 4; ni++)
        acc[mi][ni] = __builtin_amdgcn_mfma_f32_16x16x32_bf16(af[mi], bfr[ni],
                                                              acc[mi][ni], 0, 0, 0);
  }

#pragma unroll
  for (int mi = 0; mi < 4; mi++) {
#pragma unroll
    for (int ni = 0; ni < 4; ni++) {
      int col = n0 + wn + ni * 16 + ml;
      if (col < N) {
#pragma unroll
        for (int j = 0; j < 4; j++) {
          int row = m0 + wm + mi * 16 + quad * 4 + j;
          float v = acc[mi][ni][j];
          if (OUT_BF16)
            ((__hip_bfloat16*)Cp)[(size_t)row * N + col] = __float2bfloat16(v);
          else
            ((float*)Cp)[(size_t)row * N + col] = v;
        }
      }
    }
  }
}

// ---------------- RoPE on q_pe (in place, bf16 q [BS][NH*192]) ----------------
__global__ __launch_bounds__(256) void rope_q_kernel(__hip_bfloat16* __restrict__ q,
                                                     const float* __restrict__ freqs) {
  int si = blockIdx.x;
  int s  = si & (S_LEN - 1);
  int tid = threadIdx.x;
  for (int p = tid; p < NH * 32; p += 256) {
    int h = p >> 5, i = p & 31;
    size_t base = (size_t)si * (NH * DQK) + h * DQK + 128 + 2 * i;
    float c  = freqs[s * 64 + 2 * i];
    float sn = freqs[s * 64 + 2 * i + 1];
    float x0 = __bfloat162float(q[base]);
    float x1 = __bfloat162float(q[base + 1]);
    q[base]     = __float2bfloat16(x0 * c - x1 * sn);
    q[base + 1] = __float2bfloat16(x0 * sn + x1 * c);
  }
}

// -------- RMSNorm(kv latent) -> bf16, RoPE(k_pe) -> bf16 ---------------------
__global__ __launch_bounds__(256) void rms_rope_kv_kernel(
    const float* __restrict__ kva, const float* __restrict__ w,
    const float* __restrict__ freqs, __hip_bfloat16* __restrict__ latent,
    __hip_bfloat16* __restrict__ kpe_out) {
  int si = blockIdx.x;
  int tid = threadIdx.x;
  const float* row = kva + (size_t)si * 576;
  float v0 = row[tid], v1 = row[tid + 256];
  float ss = v0 * v0 + v1 * v1;
#pragma unroll
  for (int off = 1; off < 64; off <<= 1) ss += __shfl_xor(ss, off, 64);
  __shared__ float red[4];
  if ((tid & 63) == 0) red[tid >> 6] = ss;
  __syncthreads();
  float tot = red[0] + red[1] + red[2] + red[3];
  float r = rsqrtf(tot / 512.0f + 1e-6f);
  latent[(size_t)si * 512 + tid]       = __float2bfloat16(v0 * r * w[tid]);
  latent[(size_t)si * 512 + tid + 256] = __float2bfloat16(v1 * r * w[tid + 256]);
  if (tid < 32) {
    int s = si & (S_LEN - 1);
    float c  = freqs[s * 64 + 2 * tid];
    float sn = freqs[s * 64 + 2 * tid + 1];
    float x0 = row[512 + 2 * tid], x1 = row[512 + 2 * tid + 1];
    kpe_out[(size_t)si * 64 + 2 * tid]     = __float2bfloat16(x0 * c - x1 * sn);
    kpe_out[(size_t)si * 64 + 2 * tid + 1] = __float2bfloat16(x0 * sn + x1 * c);
  }
}

// ---------------- 32x32-fragment MFMA flash attention, double-buffered ---------
// grid 256 blocks (qt2 slowest: id>>5); 512 threads = 8 waves x 32 q = 256 q.
// K-tile 64, K/V LDS double-buffered, ONE barrier per tile:
//   issue loads(t+1) -> compute(t) from buf -> vmcnt -> write(t+1) -> barrier.
// S^T = K.Q^T (q on col=lane&31); P in registers via shfl_xor(32) exchange;
// PV as O^T = V^T.P^T; exp2-domain online softmax.
__global__ __launch_bounds__(512, 2) void attn_mfma_kernel(
    const __hip_bfloat16* __restrict__ qb,    // [BS][NH*192]
    const __hip_bfloat16* __restrict__ kvup,  // [BS][NH*256] (nope|v per head)
    const __hip_bfloat16* __restrict__ kpe,   // [BS][64] bf16
    __hip_bfloat16* __restrict__ attn_out) {  // [BS][NH*128]
  constexpr int KS = 200;   // Ks row stride (bf16 elems) -> 4-way residual bank
  constexpr int VS = 36;    // Vt2 row stride (dwords)
  __shared__ alignas(16) unsigned short Ks[2][64 * KS];    // 2 x 25600 B
  __shared__ alignas(16) unsigned int   Vt2[2][128 * VS];  // 2 x 18432 B

  const int id  = blockIdx.x;
  const int qt2 = id >> 5;          // 0..7, slowest -> XCD-balanced
  const int hb  = id & 31;
  const int h   = hb >> 1, b = hb & 1;

  const int tid = threadIdx.x, wave = tid >> 6, lane = tid & 63;
  const int l31 = lane & 31, hh = lane >> 5;
  const int qwb = qt2 * 256 + wave * 32;  // wave's q base
  const int qg  = qwb + l31;              // lane's q (col = lane&31)
  const float qs2 = 0.07216878364870322f * 1.4426950408889634f;  // scale*log2e

  // resident Q B-frags: col=l31 -> q row qg; d = s*16 + hh*8 + e
  bf16x8 Qf[12];
  {
    const unsigned short* qrow = (const unsigned short*)qb +
        (size_t)(b * S_LEN + qg) * (NH * DQK) + h * DQK;
#pragma unroll
    for (int s = 0; s < 12; s++)
      Qf[s] = *(const bf16x8*)(qrow + s * 16 + hh * 8);
  }

  const int m16 = tid & 15;           // V staging: d-chunk owner
  const int hp  = tid >> 4;           // V staging: kpos-pair 0..31
  const int vkey = (m16 & 7) << 2;    // V write swizzle (row d>>3 = m16)
  const unsigned short* kvbase = (const unsigned short*)kvup;
  const unsigned short* kpbase = (const unsigned short*)kpe;

  float m_i = -1e30f, l_i = 0.0f;
  f32x16 O2[4];  // O^T: tile mt covers v = mt*32 + (r&3)+8*(r>>2)+4*hh, q = l31
#pragma unroll
  for (int mt = 0; mt < 4; mt++)
#pragma unroll
    for (int j = 0; j < 16; j++) O2[mt][j] = 0.0f;

  const int nkt = 4 * qt2 + 4;

  // K staging geometry: slot = tid + it*512 -> row r = slot/24, chunk c = slot%24
  // V staging: Vpre[0/1] = kpos rows 2hp, 2hp+1, d-chunk m16*8..+7
  us8 Kpre[3], Vpre[2];

  // ---- prologue: load tile 0, write buf 0, barrier ----
  {
#pragma unroll
    for (int it = 0; it < 3; it++) {
      int slot = tid + it * 512;
      int r = slot / 24, c = slot - r * 24;
      size_t grow = (size_t)(b * S_LEN + r);
      Kpre[it] = (c < 16)
          ? *(const us8*)(kvbase + grow * (NH * 256) + h * 256 + c * 8)
          : *(const us8*)(kpbase + grow * 64 + (c - 16) * 8);
    }
    const unsigned short* v0 = kvbase +
        (size_t)(b * S_LEN + 2 * hp) * (NH * 256) + h * 256 + 128 + m16 * 8;
    Vpre[0] = *(const us8*)v0;
    Vpre[1] = *(const us8*)(v0 + NH * 256);
#pragma unroll
    for (int it = 0; it < 3; it++) {
      int slot = tid + it * 512;
      int r = slot / 24, c = slot - r * 24;
      *(us8*)&Ks[0][r * KS + c * 8] = Kpre[it];
    }
#pragma unroll
    for (int z = 0; z < 8; z++) {
      int d = m16 * 8 + z;
      Vt2[0][d * VS + (hp ^ vkey)] =
          (unsigned)(unsigned short)Vpre[0][z] |
          ((unsigned)(unsigned short)Vpre[1][z] << 16);
    }
    __syncthreads();
  }

  int cur = 0;
  for (int kt = 0; kt < nkt; kt++) {
    const int kb = kt * 64;
    const unsigned short* ksc = Ks[cur];
    const unsigned int*   vtc = Vt2[cur];

    // ---- issue global->reg loads for tile kt+1 (hide under compute) ----
    const int havenext = (kt + 1 < nkt);
    if (havenext) {
      const int kb2 = kb + 64;
#pragma unroll
      for (int it = 0; it < 3; it++) {
        int slot = tid + it * 512;
        int r = slot / 24, c = slot - r * 24;
        size_t grow = (size_t)(b * S_LEN + kb2 + r);
        Kpre[it] = (c < 16)
            ? *(const us8*)(kvbase + grow * (NH * 256) + h * 256 + c * 8)
            : *(const us8*)(kpbase + grow * 64 + (c - 16) * 8);
      }
      const unsigned short* v0 = kvbase +
          (size_t)(b * S_LEN + kb2 + 2 * hp) * (NH * 256) + h * 256 + 128 + m16 * 8;
      Vpre[0] = *(const us8*)v0;
      Vpre[1] = *(const us8*)(v0 + NH * 256);
    }

    // ---- compute tile kt (guarded, NOT continue: barrier is below) ----
    if (kb <= qwb + 31) {
      // S^T = K.Q^T (32x32x16): rows kpos, cols q=l31
      f32x16 st2[2];
      __builtin_amdgcn_s_setprio(1);
#pragma unroll
      for (int mt = 0; mt < 2; mt++) {
        f32x16 acc;
#pragma unroll
        for (int j = 0; j < 16; j++) acc[j] = 0.0f;
#pragma unroll
        for (int s = 0; s < 12; s++) {
          bf16x8 kf = *(const bf16x8*)&ksc[(mt * 32 + l31) * KS + s * 16 + hh * 8];
          acc = __builtin_amdgcn_mfma_f32_32x32x16_bf16(kf, Qf[s], acc, 0, 0, 0);
        }
        st2[mt] = acc;
      }
      __builtin_amdgcn_s_setprio(0);

      // online softmax (exp2 domain); lane owns q = qg
      float mloc = -1e30f;
      if (kb + 64 <= qwb) {  // fully below diagonal
#pragma unroll
        for (int mt = 0; mt < 2; mt++)
#pragma unroll
          for (int r = 0; r < 16; r++) {
            float s = st2[mt][r] * qs2;
            st2[mt][r] = s;
            mloc = fmaxf(mloc, s);
          }
      } else {
#pragma unroll
        for (int mt = 0; mt < 2; mt++)
#pragma unroll
          for (int r = 0; r < 16; r++) {
            int kpos = kb + mt * 32 + (r & 3) + 8 * (r >> 2) + 4 * hh;
            float s = st2[mt][r] * qs2;
            s = (kpos > qg) ? -1e30f : s;
            st2[mt][r] = s;
            mloc = fmaxf(mloc, s);
          }
      }
      mloc = fmaxf(mloc, __shfl_xor(mloc, 32, 64));
      float m_new = fmaxf(m_i, mloc);
      float alpha = exp2f(m_i - m_new);
      float psum = 0.0f;
#pragma unroll
      for (int mt = 0; mt < 2; mt++)
#pragma unroll
        for (int r = 0; r < 16; r++) {
          float p = exp2f(st2[mt][r] - m_new);
          st2[mt][r] = p;
          psum += p;
        }
      psum += __shfl_xor(psum, 32, 64);
      l_i = l_i * alpha + psum;
      m_i = m_new;

      // rescale O^T: q = l31 on all regs -> lane-local alpha
#pragma unroll
      for (int mt = 0; mt < 4; mt++)
#pragma unroll
        for (int j = 0; j < 16; j++) O2[mt][j] *= alpha;

      // P -> PV B-frags in registers; cross-half exchange via shfl_xor(32)
      bf16x8 pf[4];
#pragma unroll
      for (int ss = 0; ss < 4; ss++) {
        const int pmt = ss >> 1, gg = ss & 1;
        unsigned int U0 = pack2bf(st2[pmt][gg * 8 + 0], st2[pmt][gg * 8 + 1]);
        unsigned int U1 = pack2bf(st2[pmt][gg * 8 + 2], st2[pmt][gg * 8 + 3]);
        unsigned int U2 = pack2bf(st2[pmt][gg * 8 + 4], st2[pmt][gg * 8 + 5]);
        unsigned int U3 = pack2bf(st2[pmt][gg * 8 + 6], st2[pmt][gg * 8 + 7]);
        unsigned int E0 = __shfl_xor(hh ? U0 : U2, 32, 64);
        unsigned int E1 = __shfl_xor(hh ? U1 : U3, 32, 64);
        ui4 pd;
        pd.x = hh ? E0 : U0;   // offsets gg*16 + hh*8 + (0,1)
        pd.y = hh ? E1 : U1;   //                      + (2,3)
        pd.z = hh ? U2 : E0;   //                      + (4,5)
        pd.w = hh ? U3 : E1;   //                      + (6,7)
        pf[ss] = __builtin_bit_cast(bf16x8, pd);
      }

      // PV as O^T = V^T.P^T
      __builtin_amdgcn_s_setprio(1);
#pragma unroll
      for (int ss = 0; ss < 4; ss++) {
#pragma unroll
        for (int mt = 0; mt < 4; mt++) {
          int v = mt * 32 + l31;
          const unsigned int* vp =
              &vtc[v * VS + ((ss * 8 + hh * 4) ^ (((v >> 3) & 7) << 2))];
          bf16x8 bv = *(const bf16x8*)vp;
          O2[mt] = __builtin_amdgcn_mfma_f32_32x32x16_bf16(bv, pf[ss], O2[mt], 0, 0, 0);
        }
      }
      __builtin_amdgcn_s_setprio(0);
    }

    // ---- write tile kt+1 into buf^1 (vmcnt wait via data dep), barrier ----
    if (havenext) {
#pragma unroll
      for (int it = 0; it < 3; it++) {
        int slot = tid + it * 512;
        int r = slot / 24, c = slot - r * 24;
        *(us8*)&Ks[cur ^ 1][r * KS + c * 8] = Kpre[it];
      }
#pragma unroll
      for (int z = 0; z < 8; z++) {
        int d = m16 * 8 + z;
        Vt2[cur ^ 1][d * VS + (hp ^ vkey)] =
            (unsigned)(unsigned short)Vpre[0][z] |
            ((unsigned)(unsigned short)Vpre[1][z] << 16);
      }
      __syncthreads();
      cur ^= 1;
    }
  }

  // ---- epilogue: O^T reg r of mt = v = mt*32 + (r&3)+8*(r>>2)+4*hh, q = qg ----
  float invl = 1.0f / l_i;
  size_t orow = (size_t)(b * S_LEN + qg) * (NH * DV) + h * DV;
#pragma unroll
  for (int mt = 0; mt < 4; mt++) {
#pragma unroll
    for (int g = 0; g < 4; g++) {
      us4 pk;
#pragma unroll
      for (int j = 0; j < 4; j++) pk[j] = f2bf(O2[mt][g * 4 + j] * invl);
      *(us4*)((unsigned short*)attn_out + orow + mt * 32 + g * 8 + hh * 4) = pk;
    }
  }
}

// ---------------- launch ----------------
extern "C" void kernel_launch(void* const* d_in, const int* in_sizes, int n_in,
                              void* d_out, int out_size, void* d_ws, size_t ws_size,
                              hipStream_t stream) {
  const float* x     = (const float*)d_in[0];
  const float* freqs = (const float*)d_in[2];
  const float* wq    = (const float*)d_in[4];
  const float* wkva  = (const float*)d_in[5];
  const float* wkvb  = (const float*)d_in[6];
  const float* wo    = (const float*)d_in[7];
  const float* kvnw  = (const float*)d_in[8];
  float* out = (float*)d_out;

  char* ws = (char*)d_ws;
  size_t off = 0;
  auto alloc = [&](size_t bytes) {
    void* p = ws + off;
    off += (bytes + 255) & ~(size_t)255;
    return p;
  };
  __hip_bfloat16* x_bf    = (__hip_bfloat16*)alloc((size_t)BS_TOT * 2048 * 2);
  __hip_bfloat16* wq_bf   = (__hip_bfloat16*)alloc((size_t)3072 * 2048 * 2);
  __hip_bfloat16* wkva_bf = (__hip_bfloat16*)alloc((size_t)640 * 2048 * 2);  // padded
  __hip_bfloat16* wkvb_bf = (__hip_bfloat16*)alloc((size_t)4096 * 512 * 2);
  __hip_bfloat16* wo_bf   = (__hip_bfloat16*)alloc((size_t)2048 * 2048 * 2);
  __hip_bfloat16* q_bf    = (__hip_bfloat16*)alloc((size_t)BS_TOT * 3072 * 2);
  float*          kva     = (float*)alloc((size_t)BS_TOT * 576 * 4);
  __hip_bfloat16* latent  = (__hip_bfloat16*)alloc((size_t)BS_TOT * 512 * 2);
  __hip_bfloat16* kpe     = (__hip_bfloat16*)alloc((size_t)BS_TOT * 64 * 2);
  __hip_bfloat16* kvup    = (__hip_bfloat16*)alloc((size_t)BS_TOT * 4096 * 2);
  __hip_bfloat16* attn    = (__hip_bfloat16*)alloc((size_t)BS_TOT * 2048 * 2);

  cast_f32_bf16_kernel<<<2048, 256, 0, stream>>>(x, x_bf, BS_TOT * 2048,
                                                 BS_TOT * 2048);
  cast_f32_bf16_kernel<<<2048, 256, 0, stream>>>(wq, wq_bf, 3072 * 2048,
                                                 3072 * 2048);
  cast_f32_bf16_kernel<<<1024, 256, 0, stream>>>(wkva, wkva_bf, 576 * 2048,
                                                 640 * 2048);
  cast_f32_bf16_kernel<<<1024, 256, 0, stream>>>(wkvb, wkvb_bf, 4096 * 512,
                                                 4096 * 512);
  cast_f32_bf16_kernel<<<2048, 256, 0, stream>>>(wo, wo_bf, 2048 * 2048,
                                                 2048 * 2048);

  gemm_bt<1><<<dim3(3072 / 128, BS_TOT / 128), 256, 0, stream>>>(
      x_bf, wq_bf, q_bf, BS_TOT, 3072, 2048);
  rope_q_kernel<<<BS_TOT, 256, 0, stream>>>(q_bf, freqs);

  gemm_bt<0><<<dim3(5, BS_TOT / 128), 256, 0, stream>>>(
      x_bf, wkva_bf, kva, BS_TOT, 576, 2048);
  rms_rope_kv_kernel<<<BS_TOT, 256, 0, stream>>>(kva, kvnw, freqs, latent, kpe);

  gemm_bt<1><<<dim3(4096 / 128, BS_TOT / 128), 256, 0, stream>>>(
      latent, wkvb_bf, kvup, BS_TOT, 4096, 512);

  attn_mfma_kernel<<<dim3(256, 1, 1), 512, 0, stream>>>(
      q_bf, kvup, kpe, attn);

  gemm_bt<0><<<dim3(2048 / 128, BS_TOT / 128), 256, 0, stream>>>(
      attn, wo_bf, out, BS_TOT, 2048, 2048);
}

// Round 7
// 320.310 us; speedup vs baseline: 1.2428x; 1.0747x over previous
//
#include <hip/hip_runtime.h>
#include <hip/hip_bf16.h>

// MLA prefill: B=2,S=2048,DIM=2048,NH=16,D_NOPE=128,D_ROPE=64,D_V=128,KV_RANK=512
// R11: deterministic causal load-balance via in-block split-K pairing.
// R10 counters: occupancy 12.5% = 25% peak x 0.5625 work-profile -> the qt2=7
// straggler (32 serial tiles vs mean 18) is the remaining 53us. Now each block
// runs TWO items back-to-back: (qt2=x, K-half0) then (qt2=7-x, K-half1) ->
// uniform 18 tiles/block. Items write unnormalized partials (O bf16, m/l f32)
// into DEAD workspace regions (x_bf / wq_bf.. / kva — all consumed before attn);
// a light combine kernel merges the two halves per q. Pipeline/fragment math
// identical to R10 (double-buffered K/V, 1 barrier/tile, async-STAGE split,
// 32x32x16 QK/PV, in-reg P via shfl_xor, exp2 softmax).
// GEMMs: global_load_lds width-16 (m97), unchanged.

typedef __bf16 bf16x8 __attribute__((ext_vector_type(8)));
typedef float  f32x4  __attribute__((ext_vector_type(4)));
typedef float  f32x16 __attribute__((ext_vector_type(16)));
typedef unsigned short us8 __attribute__((ext_vector_type(8)));
typedef unsigned short us4 __attribute__((ext_vector_type(4)));
typedef unsigned int   ui4 __attribute__((ext_vector_type(4)));

#define S_LEN   2048
#define BS_TOT  4096   // B*S
#define NH      16
#define DQK     192
#define DV      128
#define KV_RANK 512

__device__ inline unsigned short f2bf(float f) {
  __hip_bfloat16 h = __float2bfloat16(f);
  return *reinterpret_cast<unsigned short*>(&h);
}
__device__ inline float bfu2f(unsigned short u) {
  unsigned int x = ((unsigned int)u) << 16;
  return __builtin_bit_cast(float, x);
}
__device__ inline unsigned int pack2bf(float a, float b) {
  return (unsigned int)f2bf(a) | ((unsigned int)f2bf(b) << 16);
}
__device__ inline void glds16(const void* g, void* l) {
  __builtin_amdgcn_global_load_lds(
      (const __attribute__((address_space(1))) unsigned int*)g,
      (__attribute__((address_space(3))) unsigned int*)l, 16, 0, 0);
}

// ---------------- f32 -> bf16 cast (with zero pad to npad) ----------------
__global__ void cast_f32_bf16_kernel(const float* __restrict__ src,
                                     __hip_bfloat16* __restrict__ dst,
                                     int n, int npad) {
  int tid = blockIdx.x * blockDim.x + threadIdx.x;
  int stride = gridDim.x * blockDim.x;
  for (int i = tid * 4; i < npad; i += stride * 4) {
    if (i < n) {
      f32x4 v = *(const f32x4*)(src + i);
      dst[i + 0] = __float2bfloat16(v.x);
      dst[i + 1] = __float2bfloat16(v.y);
      dst[i + 2] = __float2bfloat16(v.z);
      dst[i + 3] = __float2bfloat16(v.w);
    } else {
      dst[i + 0] = __float2bfloat16(0.f);
      dst[i + 1] = __float2bfloat16(0.f);
      dst[i + 2] = __float2bfloat16(0.f);
      dst[i + 3] = __float2bfloat16(0.f);
    }
  }
}

// ---------------- bf16 MFMA GEMM: C[M,N] = A[M,K] @ Bw[N,K]^T ----------------
template<int OUT_BF16>
__global__ __launch_bounds__(256) void gemm_bt(const __hip_bfloat16* __restrict__ A,
                                               const __hip_bfloat16* __restrict__ Bw,
                                               void* __restrict__ Cp,
                                               int M, int N, int K) {
  constexpr int BM = 128, BN = 128, BK = 32;
  __shared__ alignas(16) unsigned short As[BM * BK];
  __shared__ alignas(16) unsigned short Bs[BN * BK];
  const int tid  = threadIdx.x;
  const int m0   = blockIdx.y * BM, n0 = blockIdx.x * BN;
  const int w    = tid >> 6, lane = tid & 63;
  const int wm   = (w >> 1) * 64, wn = (w & 1) * 64;
  const int ml   = lane & 15, quad = lane >> 4;
  const int srow = w * 16 + (lane >> 2);   // staging row within 64-row half
  const int scol = (lane & 3) * 8;         // staging col (elems)

  f32x4 acc[4][4];
#pragma unroll
  for (int i = 0; i < 4; i++)
#pragma unroll
    for (int j = 0; j < 4; j++)
#pragma unroll
      for (int e = 0; e < 4; e++) acc[i][j][e] = 0.0f;

  const unsigned short* Ag = (const unsigned short*)A;
  const unsigned short* Bg = (const unsigned short*)Bw;
  const unsigned short* a0 = Ag + (size_t)(m0 + srow) * K + scol;
  const unsigned short* a1 = Ag + (size_t)(m0 + srow + 64) * K + scol;
  const unsigned short* b0 = Bg + (size_t)(n0 + srow) * K + scol;
  const unsigned short* b1 = Bg + (size_t)(n0 + srow + 64) * K + scol;
  unsigned short* lA0 = &As[(w * 16) * BK];        // wave-uniform LDS bases
  unsigned short* lA1 = &As[(64 + w * 16) * BK];
  unsigned short* lB0 = &Bs[(w * 16) * BK];
  unsigned short* lB1 = &Bs[(64 + w * 16) * BK];

  for (int k0 = 0; k0 < K; k0 += BK) {
    __syncthreads();
    glds16(a0 + k0, lA0);
    glds16(a1 + k0, lA1);
    glds16(b0 + k0, lB0);
    glds16(b1 + k0, lB1);
    __syncthreads();

    bf16x8 af[4], bfr[4];
#pragma unroll
    for (int mi = 0; mi < 4; mi++)
      af[mi] = *(const bf16x8*)&As[(wm + mi * 16 + ml) * BK + quad * 8];
#pragma unroll
    for (int ni = 0; ni < 4; ni++)
      bfr[ni] = *(const bf16x8*)&Bs[(wn + ni * 16 + ml) * BK + quad * 8];
#pragma unroll
    for (int mi = 0; mi < 4; mi++)
#pragma unroll
      for (int ni = 0; ni < 4; ni++)
        acc[mi][ni] = __builtin_amdgcn_mfma_f32_16x16x32_bf16(af[mi], bfr[ni],
                                                              acc[mi][ni], 0, 0, 0);
  }

#pragma unroll
  for (int mi = 0; mi < 4; mi++) {
#pragma unroll
    for (int ni = 0; ni < 4; ni++) {
      int col = n0 + wn + ni * 16 + ml;
      if (col < N) {
#pragma unroll
        for (int j = 0; j < 4; j++) {
          int row = m0 + wm + mi * 16 + quad * 4 + j;
          float v = acc[mi][ni][j];
          if (OUT_BF16)
            ((__hip_bfloat16*)Cp)[(size_t)row * N + col] = __float2bfloat16(v);
          else
            ((float*)Cp)[(size_t)row * N + col] = v;
        }
      }
    }
  }
}

// ---------------- RoPE on q_pe (in place, bf16 q [BS][NH*192]) ----------------
__global__ __launch_bounds__(256) void rope_q_kernel(__hip_bfloat16* __restrict__ q,
                                                     const float* __restrict__ freqs) {
  int si = blockIdx.x;
  int s  = si & (S_LEN - 1);
  int tid = threadIdx.x;
  for (int p = tid; p < NH * 32; p += 256) {
    int h = p >> 5, i = p & 31;
    size_t base = (size_t)si * (NH * DQK) + h * DQK + 128 + 2 * i;
    float c  = freqs[s * 64 + 2 * i];
    float sn = freqs[s * 64 + 2 * i + 1];
    float x0 = __bfloat162float(q[base]);
    float x1 = __bfloat162float(q[base + 1]);
    q[base]     = __float2bfloat16(x0 * c - x1 * sn);
    q[base + 1] = __float2bfloat16(x0 * sn + x1 * c);
  }
}

// -------- RMSNorm(kv latent) -> bf16, RoPE(k_pe) -> bf16 ---------------------
__global__ __launch_bounds__(256) void rms_rope_kv_kernel(
    const float* __restrict__ kva, const float* __restrict__ w,
    const float* __restrict__ freqs, __hip_bfloat16* __restrict__ latent,
    __hip_bfloat16* __restrict__ kpe_out) {
  int si = blockIdx.x;
  int tid = threadIdx.x;
  const float* row = kva + (size_t)si * 576;
  float v0 = row[tid], v1 = row[tid + 256];
  float ss = v0 * v0 + v1 * v1;
#pragma unroll
  for (int off = 1; off < 64; off <<= 1) ss += __shfl_xor(ss, off, 64);
  __shared__ float red[4];
  if ((tid & 63) == 0) red[tid >> 6] = ss;
  __syncthreads();
  float tot = red[0] + red[1] + red[2] + red[3];
  float r = rsqrtf(tot / 512.0f + 1e-6f);
  latent[(size_t)si * 512 + tid]       = __float2bfloat16(v0 * r * w[tid]);
  latent[(size_t)si * 512 + tid + 256] = __float2bfloat16(v1 * r * w[tid + 256]);
  if (tid < 32) {
    int s = si & (S_LEN - 1);
    float c  = freqs[s * 64 + 2 * tid];
    float sn = freqs[s * 64 + 2 * tid + 1];
    float x0 = row[512 + 2 * tid], x1 = row[512 + 2 * tid + 1];
    kpe_out[(size_t)si * 64 + 2 * tid]     = __float2bfloat16(x0 * c - x1 * sn);
    kpe_out[(size_t)si * 64 + 2 * tid + 1] = __float2bfloat16(x0 * sn + x1 * c);
  }
}

// ---------------- 32x32-fragment MFMA flash attention, split-K balanced --------
// grid 256 blocks; 512 threads = 8 waves x 32 q = 256 q. K-tile 64, dbuf LDS,
// one barrier per tile, async-STAGE split. Block x runs two items:
//   item0 = (qt2=x,   K-tiles [0, 2x+2))          -- lower half of K range
//   item1 = (qt2=7-x, K-tiles [2(7-x)+2, 4(7-x)+4)) -- upper half
// -> uniform 18 tiles/block. Each item writes unnormalized partial O (bf16)
// and per-q (m,l) f32; attn_combine merges.
__global__ __launch_bounds__(512, 2) void attn_mfma_kernel(
    const __hip_bfloat16* __restrict__ qb,    // [BS][NH*192]
    const __hip_bfloat16* __restrict__ kvup,  // [BS][NH*256] (nope|v per head)
    const __hip_bfloat16* __restrict__ kpe,   // [BS][64] bf16
    unsigned short* __restrict__ op0,         // partial O half0 [BS][NH][128] bf16
    unsigned short* __restrict__ op1,         // partial O half1
    float* __restrict__ mlp0,                 // [BS*NH][2] {m,l} half0
    float* __restrict__ mlp1) {               // half1
  constexpr int KS = 200;   // Ks row stride (bf16 elems)
  constexpr int VS = 36;    // Vt2 row stride (dwords)
  __shared__ alignas(16) unsigned short Ks[2][64 * KS];    // 2 x 25600 B
  __shared__ alignas(16) unsigned int   Vt2[2][128 * VS];  // 2 x 18432 B

  const int id = blockIdx.x;
  const int x  = id >> 5;           // 0..7
  const int hb = id & 31;
  const int h  = hb >> 1, b = hb & 1;

  const int tid = threadIdx.x, wave = tid >> 6, lane = tid & 63;
  const int l31 = lane & 31, hh = lane >> 5;
  const float qs2 = 0.07216878364870322f * 1.4426950408889634f;  // scale*log2e

  const int m16 = tid & 15;           // V staging: d-chunk owner
  const int hp  = tid >> 4;           // V staging: kpos-pair 0..31
  const int vkey = (m16 & 7) << 2;    // V write swizzle (row d>>3 = m16)
  const unsigned short* kvbase = (const unsigned short*)kvup;
  const unsigned short* kpbase = (const unsigned short*)kpe;

#pragma unroll 1
  for (int item = 0; item < 2; ++item) {
    const int qt2    = item ? (7 - x) : x;
    const int kstart = item ? (2 * qt2 + 2) : 0;   // K-half start (64-k tiles)
    const int kend   = kstart + 2 * qt2 + 2;
    const int qwb = qt2 * 256 + wave * 32;  // wave's q base
    const int qg  = qwb + l31;              // lane's q (col = lane&31)

    // resident Q B-frags: col=l31 -> q row qg; d = s*16 + hh*8 + e
    bf16x8 Qf[12];
    {
      const unsigned short* qrow = (const unsigned short*)qb +
          (size_t)(b * S_LEN + qg) * (NH * DQK) + h * DQK;
#pragma unroll
      for (int s = 0; s < 12; s++)
        Qf[s] = *(const bf16x8*)(qrow + s * 16 + hh * 8);
    }

    float m_i = -1e30f, l_i = 0.0f;
    f32x16 O2[4];  // O^T: tile mt covers v = mt*32 + (r&3)+8*(r>>2)+4*hh, q=l31
#pragma unroll
    for (int mt = 0; mt < 4; mt++)
#pragma unroll
      for (int j = 0; j < 16; j++) O2[mt][j] = 0.0f;

    us8 Kpre[3], Vpre[2];

    if (item) __syncthreads();  // previous item's waves done reading LDS

    // ---- prologue: load tile kstart, write buf 0, barrier ----
    {
      const int kb0 = kstart * 64;
#pragma unroll
      for (int it = 0; it < 3; it++) {
        int slot = tid + it * 512;
        int r = slot / 24, c = slot - r * 24;
        size_t grow = (size_t)(b * S_LEN + kb0 + r);
        Kpre[it] = (c < 16)
            ? *(const us8*)(kvbase + grow * (NH * 256) + h * 256 + c * 8)
            : *(const us8*)(kpbase + grow * 64 + (c - 16) * 8);
      }
      const unsigned short* v0 = kvbase +
          (size_t)(b * S_LEN + kb0 + 2 * hp) * (NH * 256) + h * 256 + 128 + m16 * 8;
      Vpre[0] = *(const us8*)v0;
      Vpre[1] = *(const us8*)(v0 + NH * 256);
#pragma unroll
      for (int it = 0; it < 3; it++) {
        int slot = tid + it * 512;
        int r = slot / 24, c = slot - r * 24;
        *(us8*)&Ks[0][r * KS + c * 8] = Kpre[it];
      }
#pragma unroll
      for (int z = 0; z < 8; z++) {
        int d = m16 * 8 + z;
        Vt2[0][d * VS + (hp ^ vkey)] =
            (unsigned)(unsigned short)Vpre[0][z] |
            ((unsigned)(unsigned short)Vpre[1][z] << 16);
      }
      __syncthreads();
    }

    int cur = 0;
    for (int kt = kstart; kt < kend; kt++) {
      const int kb = kt * 64;
      const unsigned short* ksc = Ks[cur];
      const unsigned int*   vtc = Vt2[cur];

      // ---- issue global->reg loads for tile kt+1 (hide under compute) ----
      const int havenext = (kt + 1 < kend);
      if (havenext) {
        const int kb2 = kb + 64;
#pragma unroll
        for (int it = 0; it < 3; it++) {
          int slot = tid + it * 512;
          int r = slot / 24, c = slot - r * 24;
          size_t grow = (size_t)(b * S_LEN + kb2 + r);
          Kpre[it] = (c < 16)
              ? *(const us8*)(kvbase + grow * (NH * 256) + h * 256 + c * 8)
              : *(const us8*)(kpbase + grow * 64 + (c - 16) * 8);
        }
        const unsigned short* v0 = kvbase +
            (size_t)(b * S_LEN + kb2 + 2 * hp) * (NH * 256) + h * 256 + 128 + m16 * 8;
        Vpre[0] = *(const us8*)v0;
        Vpre[1] = *(const us8*)(v0 + NH * 256);
      }

      // ---- compute tile kt (guarded, NOT continue: barrier is below) ----
      if (kb <= qwb + 31) {
        // S^T = K.Q^T (32x32x16): rows kpos, cols q=l31
        f32x16 st2[2];
        __builtin_amdgcn_s_setprio(1);
#pragma unroll
        for (int mt = 0; mt < 2; mt++) {
          f32x16 acc;
#pragma unroll
          for (int j = 0; j < 16; j++) acc[j] = 0.0f;
#pragma unroll
          for (int s = 0; s < 12; s++) {
            bf16x8 kf = *(const bf16x8*)&ksc[(mt * 32 + l31) * KS + s * 16 + hh * 8];
            acc = __builtin_amdgcn_mfma_f32_32x32x16_bf16(kf, Qf[s], acc, 0, 0, 0);
          }
          st2[mt] = acc;
        }
        __builtin_amdgcn_s_setprio(0);

        // online softmax (exp2 domain); lane owns q = qg
        float mloc = -1e30f;
        if (kb + 64 <= qwb) {  // fully below diagonal
#pragma unroll
          for (int mt = 0; mt < 2; mt++)
#pragma unroll
            for (int r = 0; r < 16; r++) {
              float s = st2[mt][r] * qs2;
              st2[mt][r] = s;
              mloc = fmaxf(mloc, s);
            }
        } else {
#pragma unroll
          for (int mt = 0; mt < 2; mt++)
#pragma unroll
            for (int r = 0; r < 16; r++) {
              int kpos = kb + mt * 32 + (r & 3) + 8 * (r >> 2) + 4 * hh;
              float s = st2[mt][r] * qs2;
              s = (kpos > qg) ? -1e30f : s;
              st2[mt][r] = s;
              mloc = fmaxf(mloc, s);
            }
        }
        mloc = fmaxf(mloc, __shfl_xor(mloc, 32, 64));
        float m_new = fmaxf(m_i, mloc);
        float alpha = exp2f(m_i - m_new);
        float psum = 0.0f;
#pragma unroll
        for (int mt = 0; mt < 2; mt++)
#pragma unroll
          for (int r = 0; r < 16; r++) {
            float p = exp2f(st2[mt][r] - m_new);
            st2[mt][r] = p;
            psum += p;
          }
        psum += __shfl_xor(psum, 32, 64);
        l_i = l_i * alpha + psum;
        m_i = m_new;

        // rescale O^T: q = l31 on all regs -> lane-local alpha
#pragma unroll
        for (int mt = 0; mt < 4; mt++)
#pragma unroll
          for (int j = 0; j < 16; j++) O2[mt][j] *= alpha;

        // P -> PV B-frags in registers; cross-half exchange via shfl_xor(32)
        bf16x8 pf[4];
#pragma unroll
        for (int ss = 0; ss < 4; ss++) {
          const int pmt = ss >> 1, gg = ss & 1;
          unsigned int U0 = pack2bf(st2[pmt][gg * 8 + 0], st2[pmt][gg * 8 + 1]);
          unsigned int U1 = pack2bf(st2[pmt][gg * 8 + 2], st2[pmt][gg * 8 + 3]);
          unsigned int U2 = pack2bf(st2[pmt][gg * 8 + 4], st2[pmt][gg * 8 + 5]);
          unsigned int U3 = pack2bf(st2[pmt][gg * 8 + 6], st2[pmt][gg * 8 + 7]);
          unsigned int E0 = __shfl_xor(hh ? U0 : U2, 32, 64);
          unsigned int E1 = __shfl_xor(hh ? U1 : U3, 32, 64);
          ui4 pd;
          pd.x = hh ? E0 : U0;   // offsets gg*16 + hh*8 + (0,1)
          pd.y = hh ? E1 : U1;   //                      + (2,3)
          pd.z = hh ? U2 : E0;   //                      + (4,5)
          pd.w = hh ? U3 : E1;   //                      + (6,7)
          pf[ss] = __builtin_bit_cast(bf16x8, pd);
        }

        // PV as O^T = V^T.P^T
        __builtin_amdgcn_s_setprio(1);
#pragma unroll
        for (int ss = 0; ss < 4; ss++) {
#pragma unroll
          for (int mt = 0; mt < 4; mt++) {
            int v = mt * 32 + l31;
            const unsigned int* vp =
                &vtc[v * VS + ((ss * 8 + hh * 4) ^ (((v >> 3) & 7) << 2))];
            bf16x8 bv = *(const bf16x8*)vp;
            O2[mt] = __builtin_amdgcn_mfma_f32_32x32x16_bf16(bv, pf[ss], O2[mt],
                                                             0, 0, 0);
          }
        }
        __builtin_amdgcn_s_setprio(0);
      }

      // ---- write tile kt+1 into buf^1, barrier ----
      if (havenext) {
#pragma unroll
        for (int it = 0; it < 3; it++) {
          int slot = tid + it * 512;
          int r = slot / 24, c = slot - r * 24;
          *(us8*)&Ks[cur ^ 1][r * KS + c * 8] = Kpre[it];
        }
#pragma unroll
        for (int z = 0; z < 8; z++) {
          int d = m16 * 8 + z;
          Vt2[cur ^ 1][d * VS + (hp ^ vkey)] =
              (unsigned)(unsigned short)Vpre[0][z] |
              ((unsigned)(unsigned short)Vpre[1][z] << 16);
        }
        __syncthreads();
        cur ^= 1;
      }
    }

    // ---- partial epilogue: raw O (no 1/l), plus (m,l) ----
    unsigned short* op = item ? op1 : op0;
    float* mlp = item ? mlp1 : mlp0;
    const size_t basep = (size_t)(b * S_LEN + qg) * NH + h;
    unsigned short* orow = op + basep * 128;
#pragma unroll
    for (int mt = 0; mt < 4; mt++) {
#pragma unroll
      for (int g = 0; g < 4; g++) {
        us4 pk;
#pragma unroll
        for (int j = 0; j < 4; j++) pk[j] = f2bf(O2[mt][g * 4 + j]);
        *(us4*)(orow + mt * 32 + g * 8 + hh * 4) = pk;
      }
    }
    if (hh == 0) {
      mlp[basep * 2 + 0] = m_i;
      mlp[basep * 2 + 1] = l_i;
    }
  }
}

// ---------------- combine the two K-halves per q-row ---------------------------
// grid (BS_TOT) x 256: thread -> (h = tid>>4, d-chunk = (tid&15)*8).
__global__ __launch_bounds__(256) void attn_combine_kernel(
    const unsigned short* __restrict__ op0, const unsigned short* __restrict__ op1,
    const float* __restrict__ mlp0, const float* __restrict__ mlp1,
    __hip_bfloat16* __restrict__ attn_out) {
  const int bs = blockIdx.x;
  const int tid = threadIdx.x;
  const int h = tid >> 4, dc = (tid & 15) * 8;
  const size_t basep = (size_t)bs * NH + h;
  const us8 a = *(const us8*)(op0 + basep * 128 + dc);
  const us8 c = *(const us8*)(op1 + basep * 128 + dc);
  const float m0 = mlp0[basep * 2], l0 = mlp0[basep * 2 + 1];
  const float m1 = mlp1[basep * 2], l1 = mlp1[basep * 2 + 1];
  const float m = fmaxf(m0, m1);
  const float a0 = exp2f(m0 - m), a1 = exp2f(m1 - m);
  const float inv = 1.0f / (l0 * a0 + l1 * a1);
  us8 o;
#pragma unroll
  for (int z = 0; z < 8; z++) {
    float v = (bfu2f((unsigned short)a[z]) * a0 +
               bfu2f((unsigned short)c[z]) * a1) * inv;
    o[z] = f2bf(v);
  }
  *(us8*)((unsigned short*)attn_out + (size_t)bs * (NH * DV) + h * DV + dc) = o;
}

// ---------------- launch ----------------
extern "C" void kernel_launch(void* const* d_in, const int* in_sizes, int n_in,
                              void* d_out, int out_size, void* d_ws, size_t ws_size,
                              hipStream_t stream) {
  const float* x     = (const float*)d_in[0];
  const float* freqs = (const float*)d_in[2];
  const float* wq    = (const float*)d_in[4];
  const float* wkva  = (const float*)d_in[5];
  const float* wkvb  = (const float*)d_in[6];
  const float* wo    = (const float*)d_in[7];
  const float* kvnw  = (const float*)d_in[8];
  float* out = (float*)d_out;

  char* ws = (char*)d_ws;
  size_t off = 0;
  auto alloc = [&](size_t bytes) {
    void* p = ws + off;
    off += (bytes + 255) & ~(size_t)255;
    return p;
  };
  __hip_bfloat16* x_bf    = (__hip_bfloat16*)alloc((size_t)BS_TOT * 2048 * 2);
  __hip_bfloat16* wq_bf   = (__hip_bfloat16*)alloc((size_t)3072 * 2048 * 2);
  __hip_bfloat16* wkva_bf = (__hip_bfloat16*)alloc((size_t)640 * 2048 * 2);  // padded
  __hip_bfloat16* wkvb_bf = (__hip_bfloat16*)alloc((size_t)4096 * 512 * 2);
  __hip_bfloat16* wo_bf   = (__hip_bfloat16*)alloc((size_t)2048 * 2048 * 2);
  __hip_bfloat16* q_bf    = (__hip_bfloat16*)alloc((size_t)BS_TOT * 3072 * 2);
  float*          kva     = (float*)alloc((size_t)BS_TOT * 576 * 4);
  __hip_bfloat16* latent  = (__hip_bfloat16*)alloc((size_t)BS_TOT * 512 * 2);
  __hip_bfloat16* kpe     = (__hip_bfloat16*)alloc((size_t)BS_TOT * 64 * 2);
  __hip_bfloat16* kvup    = (__hip_bfloat16*)alloc((size_t)BS_TOT * 4096 * 2);
  __hip_bfloat16* attn    = (__hip_bfloat16*)alloc((size_t)BS_TOT * 2048 * 2);

  // Partial buffers ALIAS regions that are dead by the time attention runs:
  //   op0 (16.78 MB) = x_bf region (last read: kva GEMM)
  //   op1 (16.78 MB) = wq_bf..wkvb_bf regions (19.39 MB; last reads: q/kvup GEMMs)
  //   ml  (1.05 MB)  = kva region (last read: rms_rope)
  unsigned short* op0 = (unsigned short*)x_bf;
  unsigned short* op1 = (unsigned short*)wq_bf;
  float* mlp0 = (float*)kva;
  float* mlp1 = mlp0 + (size_t)BS_TOT * NH * 2;

  cast_f32_bf16_kernel<<<2048, 256, 0, stream>>>(x, x_bf, BS_TOT * 2048,
                                                 BS_TOT * 2048);
  cast_f32_bf16_kernel<<<2048, 256, 0, stream>>>(wq, wq_bf, 3072 * 2048,
                                                 3072 * 2048);
  cast_f32_bf16_kernel<<<1024, 256, 0, stream>>>(wkva, wkva_bf, 576 * 2048,
                                                 640 * 2048);
  cast_f32_bf16_kernel<<<1024, 256, 0, stream>>>(wkvb, wkvb_bf, 4096 * 512,
                                                 4096 * 512);
  cast_f32_bf16_kernel<<<2048, 256, 0, stream>>>(wo, wo_bf, 2048 * 2048,
                                                 2048 * 2048);

  gemm_bt<1><<<dim3(3072 / 128, BS_TOT / 128), 256, 0, stream>>>(
      x_bf, wq_bf, q_bf, BS_TOT, 3072, 2048);
  rope_q_kernel<<<BS_TOT, 256, 0, stream>>>(q_bf, freqs);

  gemm_bt<0><<<dim3(5, BS_TOT / 128), 256, 0, stream>>>(
      x_bf, wkva_bf, kva, BS_TOT, 576, 2048);
  rms_rope_kv_kernel<<<BS_TOT, 256, 0, stream>>>(kva, kvnw, freqs, latent, kpe);

  gemm_bt<1><<<dim3(4096 / 128, BS_TOT / 128), 256, 0, stream>>>(
      latent, wkvb_bf, kvup, BS_TOT, 4096, 512);

  attn_mfma_kernel<<<dim3(256, 1, 1), 512, 0, stream>>>(
      q_bf, kvup, kpe, op0, op1, mlp0, mlp1);
  attn_combine_kernel<<<dim3(BS_TOT, 1, 1), 256, 0, stream>>>(
      op0, op1, mlp0, mlp1, attn);

  gemm_bt<0><<<dim3(2048 / 128, BS_TOT / 128), 256, 0, stream>>>(
      attn, wo_bf, out, BS_TOT, 2048, 2048);
}

// Round 8
// 303.747 us; speedup vs baseline: 1.3106x; 1.0545x over previous
//
#include <hip/hip_runtime.h>
#include <hip/hip_bf16.h>

// MLA prefill: B=2,S=2048,DIM=2048,NH=16,D_NOPE=128,D_ROPE=64,D_V=128,KV_RANK=512
// R12: consolidation round.
//  (1) kva GEMM merged into q GEMM: wq_bf/wkva_bf are contiguous -> one
//      N=3712 GEMM (grid 29x32) writes fused [BS][3712] (q | kv_a). rms_rope
//      reads bf16 kv_a at stride 3712; f32 kva buffer and its GEMM deleted.
//  (2) 5 cast kernels fused into one statically-partitioned launch.
//  (3) attn defer-max (T13): skip O-rescale when __all(mloc <= m_i+8);
//      P bounded by 2^8, bf16-safe (m214-verified technique).
// Attention otherwise identical to R11 (split-K balanced, dbuf, 1 barrier/tile,
// 32x32x16 QK/PV, in-reg P via shfl_xor, exp2 softmax, partials+combine).

typedef __bf16 bf16x8 __attribute__((ext_vector_type(8)));
typedef float  f32x4  __attribute__((ext_vector_type(4)));
typedef float  f32x16 __attribute__((ext_vector_type(16)));
typedef unsigned short us8 __attribute__((ext_vector_type(8)));
typedef unsigned short us4 __attribute__((ext_vector_type(4)));
typedef unsigned int   ui4 __attribute__((ext_vector_type(4)));

#define S_LEN   2048
#define BS_TOT  4096   // B*S
#define NH      16
#define DQK     192
#define DV      128
#define KV_RANK 512
#define QSTR    3712   // fused q|kv_a row stride (3072 + 640)

__device__ inline unsigned short f2bf(float f) {
  __hip_bfloat16 h = __float2bfloat16(f);
  return *reinterpret_cast<unsigned short*>(&h);
}
__device__ inline float bfu2f(unsigned short u) {
  unsigned int x = ((unsigned int)u) << 16;
  return __builtin_bit_cast(float, x);
}
__device__ inline unsigned int pack2bf(float a, float b) {
  return (unsigned int)f2bf(a) | ((unsigned int)f2bf(b) << 16);
}
__device__ inline void glds16(const void* g, void* l) {
  __builtin_amdgcn_global_load_lds(
      (const __attribute__((address_space(1))) unsigned int*)g,
      (__attribute__((address_space(3))) unsigned int*)l, 16, 0, 0);
}

// ---------------- fused f32 -> bf16 casts (5 segments, 1 launch) --------------
// Segment sizes (f32 elems): x 8388608, wq 6291456, wkva 1179648 (pad 1310720),
// wkvb 2097152, wo 4194304. Blocks partitioned statically.
__global__ __launch_bounds__(256) void cast_all_kernel(
    const float* __restrict__ x, const float* __restrict__ wq,
    const float* __restrict__ wkva, const float* __restrict__ wkvb,
    const float* __restrict__ wo,
    __hip_bfloat16* __restrict__ xb, __hip_bfloat16* __restrict__ wqb,
    __hip_bfloat16* __restrict__ wkvab, __hip_bfloat16* __restrict__ wkvbb,
    __hip_bfloat16* __restrict__ wob) {
  const int bid = blockIdx.x;
  const float* src; __hip_bfloat16* dst; int n, npad, b0, nb;
  if (bid < 771)       { src = x;    dst = xb;    n = 8388608; npad = 8388608; b0 = 0;    nb = 771; }
  else if (bid < 1349) { src = wq;   dst = wqb;   n = 6291456; npad = 6291456; b0 = 771;  nb = 578; }
  else if (bid < 1469) { src = wkva; dst = wkvab; n = 1179648; npad = 1310720; b0 = 1349; nb = 120; }
  else if (bid < 1662) { src = wkvb; dst = wkvbb; n = 2097152; npad = 2097152; b0 = 1469; nb = 193; }
  else                 { src = wo;   dst = wob;   n = 4194304; npad = 4194304; b0 = 1662; nb = 386; }
  const int tid = (bid - b0) * 256 + threadIdx.x;
  const int stride = nb * 256;
  for (int i = tid * 4; i < npad; i += stride * 4) {
    if (i + 3 < n) {
      f32x4 v = *(const f32x4*)(src + i);
      dst[i + 0] = __float2bfloat16(v.x);
      dst[i + 1] = __float2bfloat16(v.y);
      dst[i + 2] = __float2bfloat16(v.z);
      dst[i + 3] = __float2bfloat16(v.w);
    } else {
#pragma unroll
      for (int z = 0; z < 4; z++)
        dst[i + z] = __float2bfloat16((i + z < n) ? src[i + z] : 0.f);
    }
  }
}

// ---------------- bf16 MFMA GEMM: C[M,N] = A[M,K] @ Bw[N,K]^T ----------------
template<int OUT_BF16>
__global__ __launch_bounds__(256) void gemm_bt(const __hip_bfloat16* __restrict__ A,
                                               const __hip_bfloat16* __restrict__ Bw,
                                               void* __restrict__ Cp,
                                               int M, int N, int K) {
  constexpr int BM = 128, BN = 128, BK = 32;
  __shared__ alignas(16) unsigned short As[BM * BK];
  __shared__ alignas(16) unsigned short Bs[BN * BK];
  const int tid  = threadIdx.x;
  const int m0   = blockIdx.y * BM, n0 = blockIdx.x * BN;
  const int w    = tid >> 6, lane = tid & 63;
  const int wm   = (w >> 1) * 64, wn = (w & 1) * 64;
  const int ml   = lane & 15, quad = lane >> 4;
  const int srow = w * 16 + (lane >> 2);   // staging row within 64-row half
  const int scol = (lane & 3) * 8;         // staging col (elems)

  f32x4 acc[4][4];
#pragma unroll
  for (int i = 0; i < 4; i++)
#pragma unroll
    for (int j = 0; j < 4; j++)
#pragma unroll
      for (int e = 0; e < 4; e++) acc[i][j][e] = 0.0f;

  const unsigned short* Ag = (const unsigned short*)A;
  const unsigned short* Bg = (const unsigned short*)Bw;
  const unsigned short* a0 = Ag + (size_t)(m0 + srow) * K + scol;
  const unsigned short* a1 = Ag + (size_t)(m0 + srow + 64) * K + scol;
  const unsigned short* b0 = Bg + (size_t)(n0 + srow) * K + scol;
  const unsigned short* b1 = Bg + (size_t)(n0 + srow + 64) * K + scol;
  unsigned short* lA0 = &As[(w * 16) * BK];        // wave-uniform LDS bases
  unsigned short* lA1 = &As[(64 + w * 16) * BK];
  unsigned short* lB0 = &Bs[(w * 16) * BK];
  unsigned short* lB1 = &Bs[(64 + w * 16) * BK];

  for (int k0 = 0; k0 < K; k0 += BK) {
    __syncthreads();
    glds16(a0 + k0, lA0);
    glds16(a1 + k0, lA1);
    glds16(b0 + k0, lB0);
    glds16(b1 + k0, lB1);
    __syncthreads();

    bf16x8 af[4], bfr[4];
#pragma unroll
    for (int mi = 0; mi < 4; mi++)
      af[mi] = *(const bf16x8*)&As[(wm + mi * 16 + ml) * BK + quad * 8];
#pragma unroll
    for (int ni = 0; ni < 4; ni++)
      bfr[ni] = *(const bf16x8*)&Bs[(wn + ni * 16 + ml) * BK + quad * 8];
#pragma unroll
    for (int mi = 0; mi < 4; mi++)
#pragma unroll
      for (int ni = 0; ni < 4; ni++)
        acc[mi][ni] = __builtin_amdgcn_mfma_f32_16x16x32_bf16(af[mi], bfr[ni],
                                                              acc[mi][ni], 0, 0, 0);
  }

#pragma unroll
  for (int mi = 0; mi < 4; mi++) {
#pragma unroll
    for (int ni = 0; ni < 4; ni++) {
      int col = n0 + wn + ni * 16 + ml;
      if (col < N) {
#pragma unroll
        for (int j = 0; j < 4; j++) {
          int row = m0 + wm + mi * 16 + quad * 4 + j;
          float v = acc[mi][ni][j];
          if (OUT_BF16)
            ((__hip_bfloat16*)Cp)[(size_t)row * N + col] = __float2bfloat16(v);
          else
            ((float*)Cp)[(size_t)row * N + col] = v;
        }
      }
    }
  }
}

// ------------- RoPE on q_pe (in place, bf16 fused qkv [BS][3712]) -------------
__global__ __launch_bounds__(256) void rope_q_kernel(__hip_bfloat16* __restrict__ q,
                                                     const float* __restrict__ freqs) {
  int si = blockIdx.x;
  int s  = si & (S_LEN - 1);
  int tid = threadIdx.x;
  for (int p = tid; p < NH * 32; p += 256) {
    int h = p >> 5, i = p & 31;
    size_t base = (size_t)si * QSTR + h * DQK + 128 + 2 * i;
    float c  = freqs[s * 64 + 2 * i];
    float sn = freqs[s * 64 + 2 * i + 1];
    float x0 = __bfloat162float(q[base]);
    float x1 = __bfloat162float(q[base + 1]);
    q[base]     = __float2bfloat16(x0 * c - x1 * sn);
    q[base + 1] = __float2bfloat16(x0 * sn + x1 * c);
  }
}

// --- RMSNorm(kv latent) -> bf16, RoPE(k_pe) -> bf16, from fused bf16 qkv ------
__global__ __launch_bounds__(256) void rms_rope_kv_kernel(
    const __hip_bfloat16* __restrict__ qkv, const float* __restrict__ w,
    const float* __restrict__ freqs, __hip_bfloat16* __restrict__ latent,
    __hip_bfloat16* __restrict__ kpe_out) {
  int si = blockIdx.x;
  int tid = threadIdx.x;
  const unsigned short* row = (const unsigned short*)qkv + (size_t)si * QSTR + 3072;
  float v0 = bfu2f(row[tid]), v1 = bfu2f(row[tid + 256]);
  float ss = v0 * v0 + v1 * v1;
#pragma unroll
  for (int off = 1; off < 64; off <<= 1) ss += __shfl_xor(ss, off, 64);
  __shared__ float red[4];
  if ((tid & 63) == 0) red[tid >> 6] = ss;
  __syncthreads();
  float tot = red[0] + red[1] + red[2] + red[3];
  float r = rsqrtf(tot / 512.0f + 1e-6f);
  latent[(size_t)si * 512 + tid]       = __float2bfloat16(v0 * r * w[tid]);
  latent[(size_t)si * 512 + tid + 256] = __float2bfloat16(v1 * r * w[tid + 256]);
  if (tid < 32) {
    int s = si & (S_LEN - 1);
    float c  = freqs[s * 64 + 2 * tid];
    float sn = freqs[s * 64 + 2 * tid + 1];
    float x0 = bfu2f(row[512 + 2 * tid]), x1 = bfu2f(row[512 + 2 * tid + 1]);
    kpe_out[(size_t)si * 64 + 2 * tid]     = __float2bfloat16(x0 * c - x1 * sn);
    kpe_out[(size_t)si * 64 + 2 * tid + 1] = __float2bfloat16(x0 * sn + x1 * c);
  }
}

// ---------------- 32x32-fragment MFMA flash attention, split-K balanced --------
// grid 256 blocks; 512 threads = 8 waves x 32 q = 256 q. Block x runs two items:
// (qt2=x, K-half0) then (qt2=7-x, K-half1) -> uniform 18 tiles/block.
// dbuf K/V LDS, one barrier/tile, async-STAGE split, defer-max (T13).
__global__ __launch_bounds__(512, 2) void attn_mfma_kernel(
    const __hip_bfloat16* __restrict__ qb,    // fused qkv [BS][3712]
    const __hip_bfloat16* __restrict__ kvup,  // [BS][NH*256] (nope|v per head)
    const __hip_bfloat16* __restrict__ kpe,   // [BS][64] bf16
    unsigned short* __restrict__ op0,         // partial O half0 [BS][NH][128] bf16
    unsigned short* __restrict__ op1,         // partial O half1
    float* __restrict__ mlp0,                 // [BS*NH][2] {m,l} half0
    float* __restrict__ mlp1) {               // half1
  constexpr int KS = 200;   // Ks row stride (bf16 elems)
  constexpr int VS = 36;    // Vt2 row stride (dwords)
  __shared__ alignas(16) unsigned short Ks[2][64 * KS];    // 2 x 25600 B
  __shared__ alignas(16) unsigned int   Vt2[2][128 * VS];  // 2 x 18432 B

  const int id = blockIdx.x;
  const int x  = id >> 5;           // 0..7
  const int hb = id & 31;
  const int h  = hb >> 1, b = hb & 1;

  const int tid = threadIdx.x, wave = tid >> 6, lane = tid & 63;
  const int l31 = lane & 31, hh = lane >> 5;
  const float qs2 = 0.07216878364870322f * 1.4426950408889634f;  // scale*log2e

  const int m16 = tid & 15;           // V staging: d-chunk owner
  const int hp  = tid >> 4;           // V staging: kpos-pair 0..31
  const int vkey = (m16 & 7) << 2;    // V write swizzle (row d>>3 = m16)
  const unsigned short* kvbase = (const unsigned short*)kvup;
  const unsigned short* kpbase = (const unsigned short*)kpe;

#pragma unroll 1
  for (int item = 0; item < 2; ++item) {
    const int qt2    = item ? (7 - x) : x;
    const int kstart = item ? (2 * qt2 + 2) : 0;   // K-half start (64-k tiles)
    const int kend   = kstart + 2 * qt2 + 2;
    const int qwb = qt2 * 256 + wave * 32;  // wave's q base
    const int qg  = qwb + l31;              // lane's q (col = lane&31)

    // resident Q B-frags: col=l31 -> q row qg; d = s*16 + hh*8 + e
    bf16x8 Qf[12];
    {
      const unsigned short* qrow = (const unsigned short*)qb +
          (size_t)(b * S_LEN + qg) * QSTR + h * DQK;
#pragma unroll
      for (int s = 0; s < 12; s++)
        Qf[s] = *(const bf16x8*)(qrow + s * 16 + hh * 8);
    }

    float m_i = -1e30f, l_i = 0.0f;
    f32x16 O2[4];  // O^T: tile mt covers v = mt*32 + (r&3)+8*(r>>2)+4*hh, q=l31
#pragma unroll
    for (int mt = 0; mt < 4; mt++)
#pragma unroll
      for (int j = 0; j < 16; j++) O2[mt][j] = 0.0f;

    us8 Kpre[3], Vpre[2];

    if (item) __syncthreads();  // previous item's waves done reading LDS

    // ---- prologue: load tile kstart, write buf 0, barrier ----
    {
      const int kb0 = kstart * 64;
#pragma unroll
      for (int it = 0; it < 3; it++) {
        int slot = tid + it * 512;
        int r = slot / 24, c = slot - r * 24;
        size_t grow = (size_t)(b * S_LEN + kb0 + r);
        Kpre[it] = (c < 16)
            ? *(const us8*)(kvbase + grow * (NH * 256) + h * 256 + c * 8)
            : *(const us8*)(kpbase + grow * 64 + (c - 16) * 8);
      }
      const unsigned short* v0 = kvbase +
          (size_t)(b * S_LEN + kb0 + 2 * hp) * (NH * 256) + h * 256 + 128 + m16 * 8;
      Vpre[0] = *(const us8*)v0;
      Vpre[1] = *(const us8*)(v0 + NH * 256);
#pragma unroll
      for (int it = 0; it < 3; it++) {
        int slot = tid + it * 512;
        int r = slot / 24, c = slot - r * 24;
        *(us8*)&Ks[0][r * KS + c * 8] = Kpre[it];
      }
#pragma unroll
      for (int z = 0; z < 8; z++) {
        int d = m16 * 8 + z;
        Vt2[0][d * VS + (hp ^ vkey)] =
            (unsigned)(unsigned short)Vpre[0][z] |
            ((unsigned)(unsigned short)Vpre[1][z] << 16);
      }
      __syncthreads();
    }

    int cur = 0;
    for (int kt = kstart; kt < kend; kt++) {
      const int kb = kt * 64;
      const unsigned short* ksc = Ks[cur];
      const unsigned int*   vtc = Vt2[cur];

      // ---- issue global->reg loads for tile kt+1 (hide under compute) ----
      const int havenext = (kt + 1 < kend);
      if (havenext) {
        const int kb2 = kb + 64;
#pragma unroll
        for (int it = 0; it < 3; it++) {
          int slot = tid + it * 512;
          int r = slot / 24, c = slot - r * 24;
          size_t grow = (size_t)(b * S_LEN + kb2 + r);
          Kpre[it] = (c < 16)
              ? *(const us8*)(kvbase + grow * (NH * 256) + h * 256 + c * 8)
              : *(const us8*)(kpbase + grow * 64 + (c - 16) * 8);
        }
        const unsigned short* v0 = kvbase +
            (size_t)(b * S_LEN + kb2 + 2 * hp) * (NH * 256) + h * 256 + 128 + m16 * 8;
        Vpre[0] = *(const us8*)v0;
        Vpre[1] = *(const us8*)(v0 + NH * 256);
      }

      // ---- compute tile kt (guarded, NOT continue: barrier is below) ----
      if (kb <= qwb + 31) {
        // S^T = K.Q^T (32x32x16): rows kpos, cols q=l31
        f32x16 st2[2];
        __builtin_amdgcn_s_setprio(1);
#pragma unroll
        for (int mt = 0; mt < 2; mt++) {
          f32x16 acc;
#pragma unroll
          for (int j = 0; j < 16; j++) acc[j] = 0.0f;
#pragma unroll
          for (int s = 0; s < 12; s++) {
            bf16x8 kf = *(const bf16x8*)&ksc[(mt * 32 + l31) * KS + s * 16 + hh * 8];
            acc = __builtin_amdgcn_mfma_f32_32x32x16_bf16(kf, Qf[s], acc, 0, 0, 0);
          }
          st2[mt] = acc;
        }
        __builtin_amdgcn_s_setprio(0);

        // online softmax (exp2 domain); lane owns q = qg
        float mloc = -1e30f;
        if (kb + 64 <= qwb) {  // fully below diagonal
#pragma unroll
          for (int mt = 0; mt < 2; mt++)
#pragma unroll
            for (int r = 0; r < 16; r++) {
              float s = st2[mt][r] * qs2;
              st2[mt][r] = s;
              mloc = fmaxf(mloc, s);
            }
        } else {
#pragma unroll
          for (int mt = 0; mt < 2; mt++)
#pragma unroll
            for (int r = 0; r < 16; r++) {
              int kpos = kb + mt * 32 + (r & 3) + 8 * (r >> 2) + 4 * hh;
              float s = st2[mt][r] * qs2;
              s = (kpos > qg) ? -1e30f : s;
              st2[mt][r] = s;
              mloc = fmaxf(mloc, s);
            }
        }
        mloc = fmaxf(mloc, __shfl_xor(mloc, 32, 64));
        // defer-max (T13): only rescale when the running max moved > 8 (exp2).
        if (!__all(mloc <= m_i + 8.0f)) {
          float m_new = fmaxf(m_i, mloc);
          float alpha = exp2f(m_i - m_new);
          l_i *= alpha;
#pragma unroll
          for (int mt = 0; mt < 4; mt++)
#pragma unroll
            for (int j = 0; j < 16; j++) O2[mt][j] *= alpha;
          m_i = m_new;
        }
        float psum = 0.0f;
#pragma unroll
        for (int mt = 0; mt < 2; mt++)
#pragma unroll
          for (int r = 0; r < 16; r++) {
            float p = exp2f(st2[mt][r] - m_i);
            st2[mt][r] = p;
            psum += p;
          }
        psum += __shfl_xor(psum, 32, 64);
        l_i += psum;

        // P -> PV B-frags in registers; cross-half exchange via shfl_xor(32)
        bf16x8 pf[4];
#pragma unroll
        for (int ss = 0; ss < 4; ss++) {
          const int pmt = ss >> 1, gg = ss & 1;
          unsigned int U0 = pack2bf(st2[pmt][gg * 8 + 0], st2[pmt][gg * 8 + 1]);
          unsigned int U1 = pack2bf(st2[pmt][gg * 8 + 2], st2[pmt][gg * 8 + 3]);
          unsigned int U2 = pack2bf(st2[pmt][gg * 8 + 4], st2[pmt][gg * 8 + 5]);
          unsigned int U3 = pack2bf(st2[pmt][gg * 8 + 6], st2[pmt][gg * 8 + 7]);
          unsigned int E0 = __shfl_xor(hh ? U0 : U2, 32, 64);
          unsigned int E1 = __shfl_xor(hh ? U1 : U3, 32, 64);
          ui4 pd;
          pd.x = hh ? E0 : U0;   // offsets gg*16 + hh*8 + (0,1)
          pd.y = hh ? E1 : U1;   //                      + (2,3)
          pd.z = hh ? U2 : E0;   //                      + (4,5)
          pd.w = hh ? U3 : E1;   //                      + (6,7)
          pf[ss] = __builtin_bit_cast(bf16x8, pd);
        }

        // PV as O^T = V^T.P^T
        __builtin_amdgcn_s_setprio(1);
#pragma unroll
        for (int ss = 0; ss < 4; ss++) {
#pragma unroll
          for (int mt = 0; mt < 4; mt++) {
            int v = mt * 32 + l31;
            const unsigned int* vp =
                &vtc[v * VS + ((ss * 8 + hh * 4) ^ (((v >> 3) & 7) << 2))];
            bf16x8 bv = *(const bf16x8*)vp;
            O2[mt] = __builtin_amdgcn_mfma_f32_32x32x16_bf16(bv, pf[ss], O2[mt],
                                                             0, 0, 0);
          }
        }
        __builtin_amdgcn_s_setprio(0);
      }

      // ---- write tile kt+1 into buf^1, barrier ----
      if (havenext) {
#pragma unroll
        for (int it = 0; it < 3; it++) {
          int slot = tid + it * 512;
          int r = slot / 24, c = slot - r * 24;
          *(us8*)&Ks[cur ^ 1][r * KS + c * 8] = Kpre[it];
        }
#pragma unroll
        for (int z = 0; z < 8; z++) {
          int d = m16 * 8 + z;
          Vt2[cur ^ 1][d * VS + (hp ^ vkey)] =
              (unsigned)(unsigned short)Vpre[0][z] |
              ((unsigned)(unsigned short)Vpre[1][z] << 16);
        }
        __syncthreads();
        cur ^= 1;
      }
    }

    // ---- partial epilogue: raw O (no 1/l), plus (m,l) ----
    unsigned short* op = item ? op1 : op0;
    float* mlp = item ? mlp1 : mlp0;
    const size_t basep = (size_t)(b * S_LEN + qg) * NH + h;
    unsigned short* orow = op + basep * 128;
#pragma unroll
    for (int mt = 0; mt < 4; mt++) {
#pragma unroll
      for (int g = 0; g < 4; g++) {
        us4 pk;
#pragma unroll
        for (int j = 0; j < 4; j++) pk[j] = f2bf(O2[mt][g * 4 + j]);
        *(us4*)(orow + mt * 32 + g * 8 + hh * 4) = pk;
      }
    }
    if (hh == 0) {
      mlp[basep * 2 + 0] = m_i;
      mlp[basep * 2 + 1] = l_i;
    }
  }
}

// ---------------- combine the two K-halves per q-row ---------------------------
__global__ __launch_bounds__(256) void attn_combine_kernel(
    const unsigned short* __restrict__ op0, const unsigned short* __restrict__ op1,
    const float* __restrict__ mlp0, const float* __restrict__ mlp1,
    __hip_bfloat16* __restrict__ attn_out) {
  const int bs = blockIdx.x;
  const int tid = threadIdx.x;
  const int h = tid >> 4, dc = (tid & 15) * 8;
  const size_t basep = (size_t)bs * NH + h;
  const us8 a = *(const us8*)(op0 + basep * 128 + dc);
  const us8 c = *(const us8*)(op1 + basep * 128 + dc);
  const float m0 = mlp0[basep * 2], l0 = mlp0[basep * 2 + 1];
  const float m1 = mlp1[basep * 2], l1 = mlp1[basep * 2 + 1];
  const float m = fmaxf(m0, m1);
  const float a0 = exp2f(m0 - m), a1 = exp2f(m1 - m);
  const float inv = 1.0f / (l0 * a0 + l1 * a1);
  us8 o;
#pragma unroll
  for (int z = 0; z < 8; z++) {
    float v = (bfu2f((unsigned short)a[z]) * a0 +
               bfu2f((unsigned short)c[z]) * a1) * inv;
    o[z] = f2bf(v);
  }
  *(us8*)((unsigned short*)attn_out + (size_t)bs * (NH * DV) + h * DV + dc) = o;
}

// ---------------- launch ----------------
extern "C" void kernel_launch(void* const* d_in, const int* in_sizes, int n_in,
                              void* d_out, int out_size, void* d_ws, size_t ws_size,
                              hipStream_t stream) {
  const float* x     = (const float*)d_in[0];
  const float* freqs = (const float*)d_in[2];
  const float* wq    = (const float*)d_in[4];
  const float* wkva  = (const float*)d_in[5];
  const float* wkvb  = (const float*)d_in[6];
  const float* wo    = (const float*)d_in[7];
  const float* kvnw  = (const float*)d_in[8];
  float* out = (float*)d_out;

  char* ws = (char*)d_ws;
  size_t off = 0;
  auto alloc = [&](size_t bytes) {
    void* p = ws + off;
    off += (bytes + 255) & ~(size_t)255;
    return p;
  };
  __hip_bfloat16* x_bf    = (__hip_bfloat16*)alloc((size_t)BS_TOT * 2048 * 2);
  __hip_bfloat16* wq_bf   = (__hip_bfloat16*)alloc((size_t)3072 * 2048 * 2);
  __hip_bfloat16* wkva_bf = (__hip_bfloat16*)alloc((size_t)640 * 2048 * 2);  // padded; contiguous with wq_bf
  __hip_bfloat16* wkvb_bf = (__hip_bfloat16*)alloc((size_t)4096 * 512 * 2);
  __hip_bfloat16* wo_bf   = (__hip_bfloat16*)alloc((size_t)2048 * 2048 * 2);
  __hip_bfloat16* qkv_bf  = (__hip_bfloat16*)alloc((size_t)BS_TOT * QSTR * 2);
  __hip_bfloat16* latent  = (__hip_bfloat16*)alloc((size_t)BS_TOT * 512 * 2);
  __hip_bfloat16* kpe     = (__hip_bfloat16*)alloc((size_t)BS_TOT * 64 * 2);
  __hip_bfloat16* kvup    = (__hip_bfloat16*)alloc((size_t)BS_TOT * 4096 * 2);
  __hip_bfloat16* attn    = (__hip_bfloat16*)alloc((size_t)BS_TOT * 2048 * 2);

  // Partial buffers ALIAS regions dead by attention time:
  //   op0 (16.78 MB) = x_bf (last read: fused qkv GEMM)
  //   op1 (16.78 MB) = wq_bf..wkvb_bf (19.39 MB; last reads: qkv/kvup GEMMs)
  //   ml  (1.05 MB)  = latent (last read: kvup GEMM)
  unsigned short* op0 = (unsigned short*)x_bf;
  unsigned short* op1 = (unsigned short*)wq_bf;
  float* mlp0 = (float*)latent;
  float* mlp1 = mlp0 + (size_t)BS_TOT * NH * 2;

  cast_all_kernel<<<2048, 256, 0, stream>>>(x, wq, wkva, wkvb, wo,
                                            x_bf, wq_bf, wkva_bf, wkvb_bf, wo_bf);

  // fused q|kv_a GEMM: N = 3072 + 640 = 3712 (wq_bf & wkva_bf contiguous)
  gemm_bt<1><<<dim3(QSTR / 128, BS_TOT / 128), 256, 0, stream>>>(
      x_bf, wq_bf, qkv_bf, BS_TOT, QSTR, 2048);
  rope_q_kernel<<<BS_TOT, 256, 0, stream>>>(qkv_bf, freqs);
  rms_rope_kv_kernel<<<BS_TOT, 256, 0, stream>>>(qkv_bf, kvnw, freqs, latent, kpe);

  gemm_bt<1><<<dim3(4096 / 128, BS_TOT / 128), 256, 0, stream>>>(
      latent, wkvb_bf, kvup, BS_TOT, 4096, 512);

  attn_mfma_kernel<<<dim3(256, 1, 1), 512, 0, stream>>>(
      qkv_bf, kvup, kpe, op0, op1, mlp0, mlp1);
  attn_combine_kernel<<<dim3(BS_TOT, 1, 1), 256, 0, stream>>>(
      op0, op1, mlp0, mlp1, attn);

  gemm_bt<0><<<dim3(2048 / 128, BS_TOT / 128), 256, 0, stream>>>(
      attn, wo_bf, out, BS_TOT, 2048, 2048);
}

// Round 9
// 266.079 us; speedup vs baseline: 1.4961x; 1.1416x over previous
//
#include <hip/hip_runtime.h>
#include <hip/hip_bf16.h>

// MLA prefill: B=2,S=2048,DIM=2048,NH=16,D_NOPE=128,D_ROPE=64,D_V=128,KV_RANK=512
// R13: GEMM schedule upgrade (T3+T4+T2+T1). R12 profile: fused qkv GEMM 118us
// at 528 TF (m97-structure level); the 256²+counted-vmcnt+swizzle structure is
// the documented 1.7x lever (m196/m198/m201). New gemm_bt256: 256x256 tile,
// BK=64, 8 waves, 2-slot 128KB LDS, global_load_lds with pre-swizzled source
// + XOR-swizzled ds_read (chunk ^= row&7), raw s_barrier + counted vmcnt(8)
// (no drain in steady state), setprio MFMA clusters, XCD-chunked block remap.
// qkv N padded 3712->3840 (zero B rows), QSTR=3840. Attention unchanged (R12:
// split-K balanced, dbuf, defer-max, partials+combine).

typedef __bf16 bf16x8 __attribute__((ext_vector_type(8)));
typedef float  f32x4  __attribute__((ext_vector_type(4)));
typedef float  f32x16 __attribute__((ext_vector_type(16)));
typedef unsigned short us8 __attribute__((ext_vector_type(8)));
typedef unsigned short us4 __attribute__((ext_vector_type(4)));
typedef unsigned int   ui4 __attribute__((ext_vector_type(4)));

#define S_LEN   2048
#define BS_TOT  4096   // B*S
#define NH      16
#define DQK     192
#define DV      128
#define KV_RANK 512
#define QSTR    3840   // fused q|kv_a row stride (3072 + 640 + 128 pad)

__device__ inline unsigned short f2bf(float f) {
  __hip_bfloat16 h = __float2bfloat16(f);
  return *reinterpret_cast<unsigned short*>(&h);
}
__device__ inline float bfu2f(unsigned short u) {
  unsigned int x = ((unsigned int)u) << 16;
  return __builtin_bit_cast(float, x);
}
__device__ inline unsigned int pack2bf(float a, float b) {
  return (unsigned int)f2bf(a) | ((unsigned int)f2bf(b) << 16);
}
__device__ inline void glds16(const void* g, void* l) {
  __builtin_amdgcn_global_load_lds(
      (const __attribute__((address_space(1))) unsigned int*)g,
      (__attribute__((address_space(3))) unsigned int*)l, 16, 0, 0);
}

// ---------------- fused f32 -> bf16 casts (5 segments, 1 launch) --------------
// wkva segment pads to 768 rows (640 + 128 extra zero rows for N=3840 GEMM).
__global__ __launch_bounds__(256) void cast_all_kernel(
    const float* __restrict__ x, const float* __restrict__ wq,
    const float* __restrict__ wkva, const float* __restrict__ wkvb,
    const float* __restrict__ wo,
    __hip_bfloat16* __restrict__ xb, __hip_bfloat16* __restrict__ wqb,
    __hip_bfloat16* __restrict__ wkvab, __hip_bfloat16* __restrict__ wkvbb,
    __hip_bfloat16* __restrict__ wob) {
  const int bid = blockIdx.x;
  const float* src; __hip_bfloat16* dst; int n, npad, b0, nb;
  if (bid < 771)       { src = x;    dst = xb;    n = 8388608; npad = 8388608; b0 = 0;    nb = 771; }
  else if (bid < 1349) { src = wq;   dst = wqb;   n = 6291456; npad = 6291456; b0 = 771;  nb = 578; }
  else if (bid < 1469) { src = wkva; dst = wkvab; n = 1179648; npad = 1572864; b0 = 1349; nb = 120; }
  else if (bid < 1662) { src = wkvb; dst = wkvbb; n = 2097152; npad = 2097152; b0 = 1469; nb = 193; }
  else                 { src = wo;   dst = wob;   n = 4194304; npad = 4194304; b0 = 1662; nb = 386; }
  const int tid = (bid - b0) * 256 + threadIdx.x;
  const int stride = nb * 256;
  for (int i = tid * 4; i < npad; i += stride * 4) {
    if (i + 3 < n) {
      f32x4 v = *(const f32x4*)(src + i);
      dst[i + 0] = __float2bfloat16(v.x);
      dst[i + 1] = __float2bfloat16(v.y);
      dst[i + 2] = __float2bfloat16(v.z);
      dst[i + 3] = __float2bfloat16(v.w);
    } else {
#pragma unroll
      for (int z = 0; z < 4; z++)
        dst[i + z] = __float2bfloat16((i + z < n) ? src[i + z] : 0.f);
    }
  }
}

// ------------- 256x256 8-wave pipelined GEMM: C = A[M,K] @ Bw[N,K]^T ----------
// BK=64, 2-slot LDS (128 KB), counted vmcnt(8), raw s_barrier (no drain),
// XOR-swizzled LDS (16B chunk c at row r holds source chunk c^(r&7)).
// Requires M%256==0, N%256==0, K%64==0, K>=128, grid = (N/256)*(M/256), %8==0.
template<int OUT_BF16>
__global__ __launch_bounds__(512, 2) void gemm_bt256(
    const __hip_bfloat16* __restrict__ A, const __hip_bfloat16* __restrict__ Bw,
    void* __restrict__ Cp, int M, int N, int K, int nbx) {
  __shared__ alignas(16) unsigned short Asl[2][256 * 64];  // 64 KB
  __shared__ alignas(16) unsigned short Bsl[2][256 * 64];  // 64 KB

  const int nwg = gridDim.x;
  const int cpx = nwg >> 3;                         // grids are %8 == 0
  const int id  = (blockIdx.x & 7) * cpx + (blockIdx.x >> 3);  // XCD chunking
  const int bx = id % nbx, by = id / nbx;
  const int m0 = by * 256, n0 = bx * 256;

  const int tid = threadIdx.x, w = tid >> 6, lane = tid & 63;
  const int wr = w >> 2, wc = w & 3;            // wave grid 2(M) x 4(N)
  const int ml = lane & 15, quad = lane >> 4;
  const int srow = w * 8 + (lane >> 3);         // staging row within 64-row call
  const int scol = ((lane & 7) ^ (lane >> 3)) * 8;  // pre-swizzled source chunk

  const unsigned short* Ag = (const unsigned short*)A + (size_t)(m0 + srow) * K + scol;
  const unsigned short* Bg = (const unsigned short*)Bw + (size_t)(n0 + srow) * K + scol;

  f32x4 acc[8][4];
#pragma unroll
  for (int i = 0; i < 8; i++)
#pragma unroll
    for (int j = 0; j < 4; j++)
#pragma unroll
      for (int e = 0; e < 4; e++) acc[i][j][e] = 0.0f;

  // stage one K-tile (A 256x64 + B 256x64) into slot: 8 glds16 per thread
  auto stage = [&](int slot, int k0) {
#pragma unroll
    for (int j = 0; j < 4; j++)
      glds16(Ag + (size_t)j * 64 * K + k0, &Asl[slot][(j * 64 + w * 8) * 64]);
#pragma unroll
    for (int j = 0; j < 4; j++)
      glds16(Bg + (size_t)j * 64 * K + k0, &Bsl[slot][(j * 64 + w * 8) * 64]);
  };

  const int nt = K / 64;
  stage(0, 0);
  stage(1, 64);
  asm volatile("s_waitcnt vmcnt(8)" ::: "memory");  // slot0 (oldest 8) landed
  __builtin_amdgcn_s_barrier();
  asm volatile("" ::: "memory");

  int slot = 0;
  for (int t = 0; t < nt; ++t) {
    const unsigned short* As = &Asl[slot][0];
    const unsigned short* Bs = &Bsl[slot][0];

    // B fragments for both n-halves (8 x ds_read_b128, swizzled)
    bf16x8 bfr[2][2][2];  // [nh][nf][ks]
#pragma unroll
    for (int nh = 0; nh < 2; nh++)
#pragma unroll
      for (int nf = 0; nf < 2; nf++) {
        int r = wc * 64 + nh * 32 + nf * 16 + ml;
        const char* rowp = (const char*)&Bs[r * 64];
#pragma unroll
        for (int ks = 0; ks < 2; ks++)
          bfr[nh][nf][ks] =
              *(const bf16x8*)(rowp + ((ks * 64 + quad * 16) ^ ((ml & 7) << 4)));
      }
#pragma unroll
    for (int mh = 0; mh < 2; mh++) {
      bf16x8 af[4][2];
#pragma unroll
      for (int mf = 0; mf < 4; mf++) {
        int r = wr * 128 + mh * 64 + mf * 16 + ml;
        const char* rowp = (const char*)&As[r * 64];
#pragma unroll
        for (int ks = 0; ks < 2; ks++)
          af[mf][ks] =
              *(const bf16x8*)(rowp + ((ks * 64 + quad * 16) ^ ((ml & 7) << 4)));
      }
      __builtin_amdgcn_s_setprio(1);
#pragma unroll
      for (int nh = 0; nh < 2; nh++)
#pragma unroll
        for (int mf = 0; mf < 4; mf++)
#pragma unroll
          for (int nf = 0; nf < 2; nf++)
#pragma unroll
            for (int ks = 0; ks < 2; ks++)
              acc[mh * 4 + mf][nh * 2 + nf] = __builtin_amdgcn_mfma_f32_16x16x32_bf16(
                  af[mf][ks], bfr[nh][nf][ks], acc[mh * 4 + mf][nh * 2 + nf], 0, 0, 0);
      __builtin_amdgcn_s_setprio(0);
    }

    asm volatile("" ::: "memory");
    __builtin_amdgcn_s_barrier();       // all waves done READING this slot
    asm volatile("" ::: "memory");
    if (t + 2 < nt) {
      stage(slot, (t + 2) * 64);        // refill freed slot
      asm volatile("s_waitcnt vmcnt(8)" ::: "memory");  // tile t+1 (oldest) landed
    } else {
      asm volatile("s_waitcnt vmcnt(0)" ::: "memory");  // tail drain
    }
    __builtin_amdgcn_s_barrier();       // slot^1 readable by everyone
    asm volatile("" ::: "memory");
    slot ^= 1;
  }

  // epilogue: C row = m0 + wr*128 + mi*16 + quad*4 + j, col = n0 + wc*64 + ni*16 + ml
#pragma unroll
  for (int mi = 0; mi < 8; mi++) {
#pragma unroll
    for (int ni = 0; ni < 4; ni++) {
      int col = n0 + wc * 64 + ni * 16 + ml;
      int rowb = m0 + wr * 128 + mi * 16 + quad * 4;
#pragma unroll
      for (int j = 0; j < 4; j++) {
        float v = acc[mi][ni][j];
        if (OUT_BF16)
          ((__hip_bfloat16*)Cp)[(size_t)(rowb + j) * N + col] = __float2bfloat16(v);
        else
          ((float*)Cp)[(size_t)(rowb + j) * N + col] = v;
      }
    }
  }
}

// ------------- RoPE on q_pe (in place, bf16 fused qkv [BS][QSTR]) -------------
__global__ __launch_bounds__(256) void rope_q_kernel(__hip_bfloat16* __restrict__ q,
                                                     const float* __restrict__ freqs) {
  int si = blockIdx.x;
  int s  = si & (S_LEN - 1);
  int tid = threadIdx.x;
  for (int p = tid; p < NH * 32; p += 256) {
    int h = p >> 5, i = p & 31;
    size_t base = (size_t)si * QSTR + h * DQK + 128 + 2 * i;
    float c  = freqs[s * 64 + 2 * i];
    float sn = freqs[s * 64 + 2 * i + 1];
    float x0 = __bfloat162float(q[base]);
    float x1 = __bfloat162float(q[base + 1]);
    q[base]     = __float2bfloat16(x0 * c - x1 * sn);
    q[base + 1] = __float2bfloat16(x0 * sn + x1 * c);
  }
}

// --- RMSNorm(kv latent) -> bf16, RoPE(k_pe) -> bf16, from fused bf16 qkv ------
__global__ __launch_bounds__(256) void rms_rope_kv_kernel(
    const __hip_bfloat16* __restrict__ qkv, const float* __restrict__ w,
    const float* __restrict__ freqs, __hip_bfloat16* __restrict__ latent,
    __hip_bfloat16* __restrict__ kpe_out) {
  int si = blockIdx.x;
  int tid = threadIdx.x;
  const unsigned short* row = (const unsigned short*)qkv + (size_t)si * QSTR + 3072;
  float v0 = bfu2f(row[tid]), v1 = bfu2f(row[tid + 256]);
  float ss = v0 * v0 + v1 * v1;
#pragma unroll
  for (int off = 1; off < 64; off <<= 1) ss += __shfl_xor(ss, off, 64);
  __shared__ float red[4];
  if ((tid & 63) == 0) red[tid >> 6] = ss;
  __syncthreads();
  float tot = red[0] + red[1] + red[2] + red[3];
  float r = rsqrtf(tot / 512.0f + 1e-6f);
  latent[(size_t)si * 512 + tid]       = __float2bfloat16(v0 * r * w[tid]);
  latent[(size_t)si * 512 + tid + 256] = __float2bfloat16(v1 * r * w[tid + 256]);
  if (tid < 32) {
    int s = si & (S_LEN - 1);
    float c  = freqs[s * 64 + 2 * tid];
    float sn = freqs[s * 64 + 2 * tid + 1];
    float x0 = bfu2f(row[512 + 2 * tid]), x1 = bfu2f(row[512 + 2 * tid + 1]);
    kpe_out[(size_t)si * 64 + 2 * tid]     = __float2bfloat16(x0 * c - x1 * sn);
    kpe_out[(size_t)si * 64 + 2 * tid + 1] = __float2bfloat16(x0 * sn + x1 * c);
  }
}

// ---------------- 32x32-fragment MFMA flash attention, split-K balanced --------
// grid 256 blocks; 512 threads = 8 waves x 32 q = 256 q. Block x runs two items:
// (qt2=x, K-half0) then (qt2=7-x, K-half1) -> uniform 18 tiles/block.
// dbuf K/V LDS, one barrier/tile, async-STAGE split, defer-max (T13).
__global__ __launch_bounds__(512, 2) void attn_mfma_kernel(
    const __hip_bfloat16* __restrict__ qb,    // fused qkv [BS][QSTR]
    const __hip_bfloat16* __restrict__ kvup,  // [BS][NH*256] (nope|v per head)
    const __hip_bfloat16* __restrict__ kpe,   // [BS][64] bf16
    unsigned short* __restrict__ op0,         // partial O half0 [BS][NH][128] bf16
    unsigned short* __restrict__ op1,         // partial O half1
    float* __restrict__ mlp0,                 // [BS*NH][2] {m,l} half0
    float* __restrict__ mlp1) {               // half1
  constexpr int KS = 200;   // Ks row stride (bf16 elems)
  constexpr int VS = 36;    // Vt2 row stride (dwords)
  __shared__ alignas(16) unsigned short Ks[2][64 * KS];    // 2 x 25600 B
  __shared__ alignas(16) unsigned int   Vt2[2][128 * VS];  // 2 x 18432 B

  const int id = blockIdx.x;
  const int x  = id >> 5;           // 0..7
  const int hb = id & 31;
  const int h  = hb >> 1, b = hb & 1;

  const int tid = threadIdx.x, wave = tid >> 6, lane = tid & 63;
  const int l31 = lane & 31, hh = lane >> 5;
  const float qs2 = 0.07216878364870322f * 1.4426950408889634f;  // scale*log2e

  const int m16 = tid & 15;           // V staging: d-chunk owner
  const int hp  = tid >> 4;           // V staging: kpos-pair 0..31
  const int vkey = (m16 & 7) << 2;    // V write swizzle (row d>>3 = m16)
  const unsigned short* kvbase = (const unsigned short*)kvup;
  const unsigned short* kpbase = (const unsigned short*)kpe;

#pragma unroll 1
  for (int item = 0; item < 2; ++item) {
    const int qt2    = item ? (7 - x) : x;
    const int kstart = item ? (2 * qt2 + 2) : 0;   // K-half start (64-k tiles)
    const int kend   = kstart + 2 * qt2 + 2;
    const int qwb = qt2 * 256 + wave * 32;  // wave's q base
    const int qg  = qwb + l31;              // lane's q (col = lane&31)

    // resident Q B-frags: col=l31 -> q row qg; d = s*16 + hh*8 + e
    bf16x8 Qf[12];
    {
      const unsigned short* qrow = (const unsigned short*)qb +
          (size_t)(b * S_LEN + qg) * QSTR + h * DQK;
#pragma unroll
      for (int s = 0; s < 12; s++)
        Qf[s] = *(const bf16x8*)(qrow + s * 16 + hh * 8);
    }

    float m_i = -1e30f, l_i = 0.0f;
    f32x16 O2[4];  // O^T: tile mt covers v = mt*32 + (r&3)+8*(r>>2)+4*hh, q=l31
#pragma unroll
    for (int mt = 0; mt < 4; mt++)
#pragma unroll
      for (int j = 0; j < 16; j++) O2[mt][j] = 0.0f;

    us8 Kpre[3], Vpre[2];

    if (item) __syncthreads();  // previous item's waves done reading LDS

    // ---- prologue: load tile kstart, write buf 0, barrier ----
    {
      const int kb0 = kstart * 64;
#pragma unroll
      for (int it = 0; it < 3; it++) {
        int slot = tid + it * 512;
        int r = slot / 24, c = slot - r * 24;
        size_t grow = (size_t)(b * S_LEN + kb0 + r);
        Kpre[it] = (c < 16)
            ? *(const us8*)(kvbase + grow * (NH * 256) + h * 256 + c * 8)
            : *(const us8*)(kpbase + grow * 64 + (c - 16) * 8);
      }
      const unsigned short* v0 = kvbase +
          (size_t)(b * S_LEN + kb0 + 2 * hp) * (NH * 256) + h * 256 + 128 + m16 * 8;
      Vpre[0] = *(const us8*)v0;
      Vpre[1] = *(const us8*)(v0 + NH * 256);
#pragma unroll
      for (int it = 0; it < 3; it++) {
        int slot = tid + it * 512;
        int r = slot / 24, c = slot - r * 24;
        *(us8*)&Ks[0][r * KS + c * 8] = Kpre[it];
      }
#pragma unroll
      for (int z = 0; z < 8; z++) {
        int d = m16 * 8 + z;
        Vt2[0][d * VS + (hp ^ vkey)] =
            (unsigned)(unsigned short)Vpre[0][z] |
            ((unsigned)(unsigned short)Vpre[1][z] << 16);
      }
      __syncthreads();
    }

    int cur = 0;
    for (int kt = kstart; kt < kend; kt++) {
      const int kb = kt * 64;
      const unsigned short* ksc = Ks[cur];
      const unsigned int*   vtc = Vt2[cur];

      // ---- issue global->reg loads for tile kt+1 (hide under compute) ----
      const int havenext = (kt + 1 < kend);
      if (havenext) {
        const int kb2 = kb + 64;
#pragma unroll
        for (int it = 0; it < 3; it++) {
          int slot = tid + it * 512;
          int r = slot / 24, c = slot - r * 24;
          size_t grow = (size_t)(b * S_LEN + kb2 + r);
          Kpre[it] = (c < 16)
              ? *(const us8*)(kvbase + grow * (NH * 256) + h * 256 + c * 8)
              : *(const us8*)(kpbase + grow * 64 + (c - 16) * 8);
        }
        const unsigned short* v0 = kvbase +
            (size_t)(b * S_LEN + kb2 + 2 * hp) * (NH * 256) + h * 256 + 128 + m16 * 8;
        Vpre[0] = *(const us8*)v0;
        Vpre[1] = *(const us8*)(v0 + NH * 256);
      }

      // ---- compute tile kt (guarded, NOT continue: barrier is below) ----
      if (kb <= qwb + 31) {
        // S^T = K.Q^T (32x32x16): rows kpos, cols q=l31
        f32x16 st2[2];
        __builtin_amdgcn_s_setprio(1);
#pragma unroll
        for (int mt = 0; mt < 2; mt++) {
          f32x16 acc;
#pragma unroll
          for (int j = 0; j < 16; j++) acc[j] = 0.0f;
#pragma unroll
          for (int s = 0; s < 12; s++) {
            bf16x8 kf = *(const bf16x8*)&ksc[(mt * 32 + l31) * KS + s * 16 + hh * 8];
            acc = __builtin_amdgcn_mfma_f32_32x32x16_bf16(kf, Qf[s], acc, 0, 0, 0);
          }
          st2[mt] = acc;
        }
        __builtin_amdgcn_s_setprio(0);

        // online softmax (exp2 domain); lane owns q = qg
        float mloc = -1e30f;
        if (kb + 64 <= qwb) {  // fully below diagonal
#pragma unroll
          for (int mt = 0; mt < 2; mt++)
#pragma unroll
            for (int r = 0; r < 16; r++) {
              float s = st2[mt][r] * qs2;
              st2[mt][r] = s;
              mloc = fmaxf(mloc, s);
            }
        } else {
#pragma unroll
          for (int mt = 0; mt < 2; mt++)
#pragma unroll
            for (int r = 0; r < 16; r++) {
              int kpos = kb + mt * 32 + (r & 3) + 8 * (r >> 2) + 4 * hh;
              float s = st2[mt][r] * qs2;
              s = (kpos > qg) ? -1e30f : s;
              st2[mt][r] = s;
              mloc = fmaxf(mloc, s);
            }
        }
        mloc = fmaxf(mloc, __shfl_xor(mloc, 32, 64));
        // defer-max (T13): only rescale when the running max moved > 8 (exp2).
        if (!__all(mloc <= m_i + 8.0f)) {
          float m_new = fmaxf(m_i, mloc);
          float alpha = exp2f(m_i - m_new);
          l_i *= alpha;
#pragma unroll
          for (int mt = 0; mt < 4; mt++)
#pragma unroll
            for (int j = 0; j < 16; j++) O2[mt][j] *= alpha;
          m_i = m_new;
        }
        float psum = 0.0f;
#pragma unroll
        for (int mt = 0; mt < 2; mt++)
#pragma unroll
          for (int r = 0; r < 16; r++) {
            float p = exp2f(st2[mt][r] - m_i);
            st2[mt][r] = p;
            psum += p;
          }
        psum += __shfl_xor(psum, 32, 64);
        l_i += psum;

        // P -> PV B-frags in registers; cross-half exchange via shfl_xor(32)
        bf16x8 pf[4];
#pragma unroll
        for (int ss = 0; ss < 4; ss++) {
          const int pmt = ss >> 1, gg = ss & 1;
          unsigned int U0 = pack2bf(st2[pmt][gg * 8 + 0], st2[pmt][gg * 8 + 1]);
          unsigned int U1 = pack2bf(st2[pmt][gg * 8 + 2], st2[pmt][gg * 8 + 3]);
          unsigned int U2 = pack2bf(st2[pmt][gg * 8 + 4], st2[pmt][gg * 8 + 5]);
          unsigned int U3 = pack2bf(st2[pmt][gg * 8 + 6], st2[pmt][gg * 8 + 7]);
          unsigned int E0 = __shfl_xor(hh ? U0 : U2, 32, 64);
          unsigned int E1 = __shfl_xor(hh ? U1 : U3, 32, 64);
          ui4 pd;
          pd.x = hh ? E0 : U0;   // offsets gg*16 + hh*8 + (0,1)
          pd.y = hh ? E1 : U1;   //                      + (2,3)
          pd.z = hh ? U2 : E0;   //                      + (4,5)
          pd.w = hh ? U3 : E1;   //                      + (6,7)
          pf[ss] = __builtin_bit_cast(bf16x8, pd);
        }

        // PV as O^T = V^T.P^T
        __builtin_amdgcn_s_setprio(1);
#pragma unroll
        for (int ss = 0; ss < 4; ss++) {
#pragma unroll
          for (int mt = 0; mt < 4; mt++) {
            int v = mt * 32 + l31;
            const unsigned int* vp =
                &vtc[v * VS + ((ss * 8 + hh * 4) ^ (((v >> 3) & 7) << 2))];
            bf16x8 bv = *(const bf16x8*)vp;
            O2[mt] = __builtin_amdgcn_mfma_f32_32x32x16_bf16(bv, pf[ss], O2[mt],
                                                             0, 0, 0);
          }
        }
        __builtin_amdgcn_s_setprio(0);
      }

      // ---- write tile kt+1 into buf^1, barrier ----
      if (havenext) {
#pragma unroll
        for (int it = 0; it < 3; it++) {
          int slot = tid + it * 512;
          int r = slot / 24, c = slot - r * 24;
          *(us8*)&Ks[cur ^ 1][r * KS + c * 8] = Kpre[it];
        }
#pragma unroll
        for (int z = 0; z < 8; z++) {
          int d = m16 * 8 + z;
          Vt2[cur ^ 1][d * VS + (hp ^ vkey)] =
              (unsigned)(unsigned short)Vpre[0][z] |
              ((unsigned)(unsigned short)Vpre[1][z] << 16);
        }
        __syncthreads();
        cur ^= 1;
      }
    }

    // ---- partial epilogue: raw O (no 1/l), plus (m,l) ----
    unsigned short* op = item ? op1 : op0;
    float* mlp = item ? mlp1 : mlp0;
    const size_t basep = (size_t)(b * S_LEN + qg) * NH + h;
    unsigned short* orow = op + basep * 128;
#pragma unroll
    for (int mt = 0; mt < 4; mt++) {
#pragma unroll
      for (int g = 0; g < 4; g++) {
        us4 pk;
#pragma unroll
        for (int j = 0; j < 4; j++) pk[j] = f2bf(O2[mt][g * 4 + j]);
        *(us4*)(orow + mt * 32 + g * 8 + hh * 4) = pk;
      }
    }
    if (hh == 0) {
      mlp[basep * 2 + 0] = m_i;
      mlp[basep * 2 + 1] = l_i;
    }
  }
}

// ---------------- combine the two K-halves per q-row ---------------------------
__global__ __launch_bounds__(256) void attn_combine_kernel(
    const unsigned short* __restrict__ op0, const unsigned short* __restrict__ op1,
    const float* __restrict__ mlp0, const float* __restrict__ mlp1,
    __hip_bfloat16* __restrict__ attn_out) {
  const int bs = blockIdx.x;
  const int tid = threadIdx.x;
  const int h = tid >> 4, dc = (tid & 15) * 8;
  const size_t basep = (size_t)bs * NH + h;
  const us8 a = *(const us8*)(op0 + basep * 128 + dc);
  const us8 c = *(const us8*)(op1 + basep * 128 + dc);
  const float m0 = mlp0[basep * 2], l0 = mlp0[basep * 2 + 1];
  const float m1 = mlp1[basep * 2], l1 = mlp1[basep * 2 + 1];
  const float m = fmaxf(m0, m1);
  const float a0 = exp2f(m0 - m), a1 = exp2f(m1 - m);
  const float inv = 1.0f / (l0 * a0 + l1 * a1);
  us8 o;
#pragma unroll
  for (int z = 0; z < 8; z++) {
    float v = (bfu2f((unsigned short)a[z]) * a0 +
               bfu2f((unsigned short)c[z]) * a1) * inv;
    o[z] = f2bf(v);
  }
  *(us8*)((unsigned short*)attn_out + (size_t)bs * (NH * DV) + h * DV + dc) = o;
}

// ---------------- launch ----------------
extern "C" void kernel_launch(void* const* d_in, const int* in_sizes, int n_in,
                              void* d_out, int out_size, void* d_ws, size_t ws_size,
                              hipStream_t stream) {
  const float* x     = (const float*)d_in[0];
  const float* freqs = (const float*)d_in[2];
  const float* wq    = (const float*)d_in[4];
  const float* wkva  = (const float*)d_in[5];
  const float* wkvb  = (const float*)d_in[6];
  const float* wo    = (const float*)d_in[7];
  const float* kvnw  = (const float*)d_in[8];
  float* out = (float*)d_out;

  char* ws = (char*)d_ws;
  size_t off = 0;
  auto alloc = [&](size_t bytes) {
    void* p = ws + off;
    off += (bytes + 255) & ~(size_t)255;
    return p;
  };
  __hip_bfloat16* x_bf    = (__hip_bfloat16*)alloc((size_t)BS_TOT * 2048 * 2);
  __hip_bfloat16* wq_bf   = (__hip_bfloat16*)alloc((size_t)3072 * 2048 * 2);
  __hip_bfloat16* wkva_bf = (__hip_bfloat16*)alloc((size_t)768 * 2048 * 2);  // 576+pad; contiguous with wq_bf -> 3840 rows
  __hip_bfloat16* wkvb_bf = (__hip_bfloat16*)alloc((size_t)4096 * 512 * 2);
  __hip_bfloat16* wo_bf   = (__hip_bfloat16*)alloc((size_t)2048 * 2048 * 2);
  __hip_bfloat16* qkv_bf  = (__hip_bfloat16*)alloc((size_t)BS_TOT * QSTR * 2);
  __hip_bfloat16* latent  = (__hip_bfloat16*)alloc((size_t)BS_TOT * 512 * 2);
  __hip_bfloat16* kpe     = (__hip_bfloat16*)alloc((size_t)BS_TOT * 64 * 2);
  __hip_bfloat16* kvup    = (__hip_bfloat16*)alloc((size_t)BS_TOT * 4096 * 2);
  __hip_bfloat16* attn    = (__hip_bfloat16*)alloc((size_t)BS_TOT * 2048 * 2);

  // Partial buffers ALIAS regions dead by attention time:
  //   op0 (16.78 MB) = x_bf (last read: fused qkv GEMM)
  //   op1 (16.78 MB) = wq_bf.. (spans wq/wkva/wkvb; all dead after kvup GEMM)
  //   ml  (1.05 MB)  = latent (last read: kvup GEMM)
  unsigned short* op0 = (unsigned short*)x_bf;
  unsigned short* op1 = (unsigned short*)wq_bf;
  float* mlp0 = (float*)latent;
  float* mlp1 = mlp0 + (size_t)BS_TOT * NH * 2;

  cast_all_kernel<<<2048, 256, 0, stream>>>(x, wq, wkva, wkvb, wo,
                                            x_bf, wq_bf, wkva_bf, wkvb_bf, wo_bf);

  // fused q|kv_a GEMM: N = 3840 (3072 + 640 + 128 zero pad rows)
  gemm_bt256<1><<<dim3(240), 512, 0, stream>>>(
      x_bf, wq_bf, qkv_bf, BS_TOT, QSTR, 2048, QSTR / 256);
  rope_q_kernel<<<BS_TOT, 256, 0, stream>>>(qkv_bf, freqs);
  rms_rope_kv_kernel<<<BS_TOT, 256, 0, stream>>>(qkv_bf, kvnw, freqs, latent, kpe);

  gemm_bt256<1><<<dim3(256), 512, 0, stream>>>(
      latent, wkvb_bf, kvup, BS_TOT, 4096, 512, 16);

  attn_mfma_kernel<<<dim3(256, 1, 1), 512, 0, stream>>>(
      qkv_bf, kvup, kpe, op0, op1, mlp0, mlp1);
  attn_combine_kernel<<<dim3(BS_TOT, 1, 1), 256, 0, stream>>>(
      op0, op1, mlp0, mlp1, attn);

  gemm_bt256<0><<<dim3(128), 512, 0, stream>>>(
      attn, wo_bf, out, BS_TOT, 2048, 2048, 8);
}

// Round 11
// 261.100 us; speedup vs baseline: 1.5247x; 1.0191x over previous
//
#include <hip/hip_runtime.h>
#include <hip/hip_bf16.h>

// MLA prefill: B=2,S=2048,DIM=2048,NH=16,D_NOPE=128,D_ROPE=64,D_V=128,KV_RANK=512
// R14 (resubmit; previous bench died with UnresponsiveContainer before running).
// attn serial-chain + VALU reduction (85us kernel, measured 2.3x above its
// LDS floor at 2 waves/SIMD):
//  (1) staging addresses hoisted to per-item pointers advanced by constant
//      strides (removes 3 int-divs + 64b muls per tile per thread);
//  (2) softmax: mask in RAW domain, single-FMA exp2 arg (p = exp2(fma(raw,
//      qs2, -m))) — deletes the 32-mul scale pass + 32 subs per tile;
//  (3) tree fmax/psum reductions (depth 31 -> 5, v_max3-fusable).
//  (4) rope_q + rms_rope merged into one kernel (disjoint columns, no sync).
// GEMMs unchanged (R13 256x256 counted-vmcnt+swizzle). Split-K attn balance,
// defer-max, partials+combine unchanged.

typedef __bf16 bf16x8 __attribute__((ext_vector_type(8)));
typedef float  f32x4  __attribute__((ext_vector_type(4)));
typedef float  f32x16 __attribute__((ext_vector_type(16)));
typedef unsigned short us8 __attribute__((ext_vector_type(8)));
typedef unsigned short us4 __attribute__((ext_vector_type(4)));
typedef unsigned int   ui4 __attribute__((ext_vector_type(4)));

#define S_LEN   2048
#define BS_TOT  4096   // B*S
#define NH      16
#define DQK     192
#define DV      128
#define KV_RANK 512
#define QSTR    3840   // fused q|kv_a row stride (3072 + 640 + 128 pad)

__device__ inline unsigned short f2bf(float f) {
  __hip_bfloat16 h = __float2bfloat16(f);
  return *reinterpret_cast<unsigned short*>(&h);
}
__device__ inline float bfu2f(unsigned short u) {
  unsigned int x = ((unsigned int)u) << 16;
  return __builtin_bit_cast(float, x);
}
__device__ inline unsigned int pack2bf(float a, float b) {
  return (unsigned int)f2bf(a) | ((unsigned int)f2bf(b) << 16);
}
__device__ inline void glds16(const void* g, void* l) {
  __builtin_amdgcn_global_load_lds(
      (const __attribute__((address_space(1))) unsigned int*)g,
      (__attribute__((address_space(3))) unsigned int*)l, 16, 0, 0);
}

// ---------------- fused f32 -> bf16 casts (5 segments, 1 launch) --------------
__global__ __launch_bounds__(256) void cast_all_kernel(
    const float* __restrict__ x, const float* __restrict__ wq,
    const float* __restrict__ wkva, const float* __restrict__ wkvb,
    const float* __restrict__ wo,
    __hip_bfloat16* __restrict__ xb, __hip_bfloat16* __restrict__ wqb,
    __hip_bfloat16* __restrict__ wkvab, __hip_bfloat16* __restrict__ wkvbb,
    __hip_bfloat16* __restrict__ wob) {
  const int bid = blockIdx.x;
  const float* src; __hip_bfloat16* dst; int n, npad, b0, nb;
  if (bid < 771)       { src = x;    dst = xb;    n = 8388608; npad = 8388608; b0 = 0;    nb = 771; }
  else if (bid < 1349) { src = wq;   dst = wqb;   n = 6291456; npad = 6291456; b0 = 771;  nb = 578; }
  else if (bid < 1469) { src = wkva; dst = wkvab; n = 1179648; npad = 1572864; b0 = 1349; nb = 120; }
  else if (bid < 1662) { src = wkvb; dst = wkvbb; n = 2097152; npad = 2097152; b0 = 1469; nb = 193; }
  else                 { src = wo;   dst = wob;   n = 4194304; npad = 4194304; b0 = 1662; nb = 386; }
  const int tid = (bid - b0) * 256 + threadIdx.x;
  const int stride = nb * 256;
  for (int i = tid * 4; i < npad; i += stride * 4) {
    if (i + 3 < n) {
      f32x4 v = *(const f32x4*)(src + i);
      dst[i + 0] = __float2bfloat16(v.x);
      dst[i + 1] = __float2bfloat16(v.y);
      dst[i + 2] = __float2bfloat16(v.z);
      dst[i + 3] = __float2bfloat16(v.w);
    } else {
#pragma unroll
      for (int z = 0; z < 4; z++)
        dst[i + z] = __float2bfloat16((i + z < n) ? src[i + z] : 0.f);
    }
  }
}

// ------------- 256x256 8-wave pipelined GEMM: C = A[M,K] @ Bw[N,K]^T ----------
template<int OUT_BF16>
__global__ __launch_bounds__(512, 2) void gemm_bt256(
    const __hip_bfloat16* __restrict__ A, const __hip_bfloat16* __restrict__ Bw,
    void* __restrict__ Cp, int M, int N, int K, int nbx) {
  __shared__ alignas(16) unsigned short Asl[2][256 * 64];  // 64 KB
  __shared__ alignas(16) unsigned short Bsl[2][256 * 64];  // 64 KB

  const int nwg = gridDim.x;
  const int cpx = nwg >> 3;
  const int id  = (blockIdx.x & 7) * cpx + (blockIdx.x >> 3);  // XCD chunking
  const int bx = id % nbx, by = id / nbx;
  const int m0 = by * 256, n0 = bx * 256;

  const int tid = threadIdx.x, w = tid >> 6, lane = tid & 63;
  const int wr = w >> 2, wc = w & 3;
  const int ml = lane & 15, quad = lane >> 4;
  const int srow = w * 8 + (lane >> 3);
  const int scol = ((lane & 7) ^ (lane >> 3)) * 8;  // pre-swizzled source chunk

  const unsigned short* Ag = (const unsigned short*)A + (size_t)(m0 + srow) * K + scol;
  const unsigned short* Bg = (const unsigned short*)Bw + (size_t)(n0 + srow) * K + scol;

  f32x4 acc[8][4];
#pragma unroll
  for (int i = 0; i < 8; i++)
#pragma unroll
    for (int j = 0; j < 4; j++)
#pragma unroll
      for (int e = 0; e < 4; e++) acc[i][j][e] = 0.0f;

  auto stage = [&](int slot, int k0) {
#pragma unroll
    for (int j = 0; j < 4; j++)
      glds16(Ag + (size_t)j * 64 * K + k0, &Asl[slot][(j * 64 + w * 8) * 64]);
#pragma unroll
    for (int j = 0; j < 4; j++)
      glds16(Bg + (size_t)j * 64 * K + k0, &Bsl[slot][(j * 64 + w * 8) * 64]);
  };

  const int nt = K / 64;
  stage(0, 0);
  stage(1, 64);
  asm volatile("s_waitcnt vmcnt(8)" ::: "memory");
  __builtin_amdgcn_s_barrier();
  asm volatile("" ::: "memory");

  int slot = 0;
  for (int t = 0; t < nt; ++t) {
    const unsigned short* As = &Asl[slot][0];
    const unsigned short* Bs = &Bsl[slot][0];

    bf16x8 bfr[2][2][2];
#pragma unroll
    for (int nh = 0; nh < 2; nh++)
#pragma unroll
      for (int nf = 0; nf < 2; nf++) {
        int r = wc * 64 + nh * 32 + nf * 16 + ml;
        const char* rowp = (const char*)&Bs[r * 64];
#pragma unroll
        for (int ks = 0; ks < 2; ks++)
          bfr[nh][nf][ks] =
              *(const bf16x8*)(rowp + ((ks * 64 + quad * 16) ^ ((ml & 7) << 4)));
      }
#pragma unroll
    for (int mh = 0; mh < 2; mh++) {
      bf16x8 af[4][2];
#pragma unroll
      for (int mf = 0; mf < 4; mf++) {
        int r = wr * 128 + mh * 64 + mf * 16 + ml;
        const char* rowp = (const char*)&As[r * 64];
#pragma unroll
        for (int ks = 0; ks < 2; ks++)
          af[mf][ks] =
              *(const bf16x8*)(rowp + ((ks * 64 + quad * 16) ^ ((ml & 7) << 4)));
      }
      __builtin_amdgcn_s_setprio(1);
#pragma unroll
      for (int nh = 0; nh < 2; nh++)
#pragma unroll
        for (int mf = 0; mf < 4; mf++)
#pragma unroll
          for (int nf = 0; nf < 2; nf++)
#pragma unroll
            for (int ks = 0; ks < 2; ks++)
              acc[mh * 4 + mf][nh * 2 + nf] = __builtin_amdgcn_mfma_f32_16x16x32_bf16(
                  af[mf][ks], bfr[nh][nf][ks], acc[mh * 4 + mf][nh * 2 + nf], 0, 0, 0);
      __builtin_amdgcn_s_setprio(0);
    }

    asm volatile("" ::: "memory");
    __builtin_amdgcn_s_barrier();
    asm volatile("" ::: "memory");
    if (t + 2 < nt) {
      stage(slot, (t + 2) * 64);
      asm volatile("s_waitcnt vmcnt(8)" ::: "memory");
    } else {
      asm volatile("s_waitcnt vmcnt(0)" ::: "memory");
    }
    __builtin_amdgcn_s_barrier();
    asm volatile("" ::: "memory");
    slot ^= 1;
  }

#pragma unroll
  for (int mi = 0; mi < 8; mi++) {
#pragma unroll
    for (int ni = 0; ni < 4; ni++) {
      int col = n0 + wc * 64 + ni * 16 + ml;
      int rowb = m0 + wr * 128 + mi * 16 + quad * 4;
#pragma unroll
      for (int j = 0; j < 4; j++) {
        float v = acc[mi][ni][j];
        if (OUT_BF16)
          ((__hip_bfloat16*)Cp)[(size_t)(rowb + j) * N + col] = __float2bfloat16(v);
        else
          ((float*)Cp)[(size_t)(rowb + j) * N + col] = v;
      }
    }
  }
}

// --- merged: RoPE(q_pe) in place + RMSNorm(kv latent) + RoPE(k_pe) -----------
// Disjoint column ranges of the same qkv row (q_pe: h*192+128..191; kv_a:
// 3072..3647) -> no synchronization needed between the two phases.
__global__ __launch_bounds__(256) void rope_rms_kernel(
    __hip_bfloat16* __restrict__ qkv, const float* __restrict__ w,
    const float* __restrict__ freqs, __hip_bfloat16* __restrict__ latent,
    __hip_bfloat16* __restrict__ kpe_out) {
  int si = blockIdx.x;
  int s  = si & (S_LEN - 1);
  int tid = threadIdx.x;
  // ---- RoPE on q_pe ----
#pragma unroll
  for (int p = tid; p < NH * 32; p += 256) {
    int h = p >> 5, i = p & 31;
    size_t base = (size_t)si * QSTR + h * DQK + 128 + 2 * i;
    float c  = freqs[s * 64 + 2 * i];
    float sn = freqs[s * 64 + 2 * i + 1];
    float x0 = __bfloat162float(qkv[base]);
    float x1 = __bfloat162float(qkv[base + 1]);
    qkv[base]     = __float2bfloat16(x0 * c - x1 * sn);
    qkv[base + 1] = __float2bfloat16(x0 * sn + x1 * c);
  }
  // ---- RMSNorm(kv_a) + RoPE(k_pe) ----
  const unsigned short* row = (const unsigned short*)qkv + (size_t)si * QSTR + 3072;
  float v0 = bfu2f(row[tid]), v1 = bfu2f(row[tid + 256]);
  float ss = v0 * v0 + v1 * v1;
#pragma unroll
  for (int off = 1; off < 64; off <<= 1) ss += __shfl_xor(ss, off, 64);
  __shared__ float red[4];
  if ((tid & 63) == 0) red[tid >> 6] = ss;
  __syncthreads();
  float tot = red[0] + red[1] + red[2] + red[3];
  float r = rsqrtf(tot / 512.0f + 1e-6f);
  latent[(size_t)si * 512 + tid]       = __float2bfloat16(v0 * r * w[tid]);
  latent[(size_t)si * 512 + tid + 256] = __float2bfloat16(v1 * r * w[tid + 256]);
  if (tid < 32) {
    float c  = freqs[s * 64 + 2 * tid];
    float sn = freqs[s * 64 + 2 * tid + 1];
    float x0 = bfu2f(row[512 + 2 * tid]), x1 = bfu2f(row[512 + 2 * tid + 1]);
    kpe_out[(size_t)si * 64 + 2 * tid]     = __float2bfloat16(x0 * c - x1 * sn);
    kpe_out[(size_t)si * 64 + 2 * tid + 1] = __float2bfloat16(x0 * sn + x1 * c);
  }
}

// ---------------- 32x32-fragment MFMA flash attention, split-K balanced --------
// grid 256 blocks; 512 threads = 8 waves x 32 q. Two items/block -> uniform 18
// tiles. dbuf K/V LDS, 1 barrier/tile, async-STAGE, defer-max. R14: hoisted
// staging pointers, raw-domain mask + FMA exp2, tree reductions.
__global__ __launch_bounds__(512, 2) void attn_mfma_kernel(
    const __hip_bfloat16* __restrict__ qb,    // fused qkv [BS][QSTR]
    const __hip_bfloat16* __restrict__ kvup,  // [BS][NH*256] (nope|v per head)
    const __hip_bfloat16* __restrict__ kpe,   // [BS][64] bf16
    unsigned short* __restrict__ op0,         // partial O half0 [BS][NH][128] bf16
    unsigned short* __restrict__ op1,         // partial O half1
    float* __restrict__ mlp0,                 // [BS*NH][2] {m,l} half0
    float* __restrict__ mlp1) {               // half1
  constexpr int KS = 200;
  constexpr int VS = 36;
  __shared__ alignas(16) unsigned short Ks[2][64 * KS];
  __shared__ alignas(16) unsigned int   Vt2[2][128 * VS];

  const int id = blockIdx.x;
  const int x  = id >> 5;
  const int hb = id & 31;
  const int h  = hb >> 1, b = hb & 1;

  const int tid = threadIdx.x, wave = tid >> 6, lane = tid & 63;
  const int l31 = lane & 31, hh = lane >> 5;
  const float qs2 = 0.07216878364870322f * 1.4426950408889634f;  // scale*log2e

  const int m16 = tid & 15;
  const int hp  = tid >> 4;
  const int vkey = (m16 & 7) << 2;
  const unsigned short* kvbase = (const unsigned short*)kvup;
  const unsigned short* kpbase = (const unsigned short*)kpe;

  // per-thread staging geometry (constants across the kernel)
  int kr_[3], kc_[3];
#pragma unroll
  for (int it = 0; it < 3; it++) {
    int slot = tid + it * 512;
    kr_[it] = slot / 24;
    kc_[it] = slot - kr_[it] * 24;
  }

#pragma unroll 1
  for (int item = 0; item < 2; ++item) {
    const int qt2    = item ? (7 - x) : x;
    const int kstart = item ? (2 * qt2 + 2) : 0;
    const int kend   = kstart + 2 * qt2 + 2;
    const int qwb = qt2 * 256 + wave * 32;
    const int qg  = qwb + l31;

    bf16x8 Qf[12];
    {
      const unsigned short* qrow = (const unsigned short*)qb +
          (size_t)(b * S_LEN + qg) * QSTR + h * DQK;
#pragma unroll
      for (int s = 0; s < 12; s++)
        Qf[s] = *(const bf16x8*)(qrow + s * 16 + hh * 8);
    }

    float m_i = -1e30f, l_i = 0.0f;
    f32x16 O2[4];
#pragma unroll
    for (int mt = 0; mt < 4; mt++)
#pragma unroll
      for (int j = 0; j < 16; j++) O2[mt][j] = 0.0f;

    us8 Kpre[3], Vpre[2];

    // hoisted staging pointers for this item (advance by constant per tile)
    const unsigned short* kptr[3];
    int kstep[3];
#pragma unroll
    for (int it = 0; it < 3; it++) {
      if (kc_[it] < 16) {
        kptr[it] = kvbase + (size_t)(b * S_LEN + kstart * 64 + kr_[it]) * (NH * 256)
                   + h * 256 + kc_[it] * 8;
        kstep[it] = 64 * NH * 256;
      } else {
        kptr[it] = kpbase + (size_t)(b * S_LEN + kstart * 64 + kr_[it]) * 64
                   + (kc_[it] - 16) * 8;
        kstep[it] = 64 * 64;
      }
    }
    const unsigned short* vptr = kvbase +
        (size_t)(b * S_LEN + kstart * 64 + 2 * hp) * (NH * 256) + h * 256 + 128 + m16 * 8;

    if (item) __syncthreads();

    // ---- prologue: load tile kstart, write buf 0, barrier ----
    {
#pragma unroll
      for (int it = 0; it < 3; it++) {
        Kpre[it] = *(const us8*)kptr[it];
        kptr[it] += kstep[it];
      }
      Vpre[0] = *(const us8*)vptr;
      Vpre[1] = *(const us8*)(vptr + NH * 256);
      vptr += 64 * NH * 256;
#pragma unroll
      for (int it = 0; it < 3; it++)
        *(us8*)&Ks[0][kr_[it] * KS + kc_[it] * 8] = Kpre[it];
#pragma unroll
      for (int z = 0; z < 8; z++) {
        int d = m16 * 8 + z;
        Vt2[0][d * VS + (hp ^ vkey)] =
            (unsigned)(unsigned short)Vpre[0][z] |
            ((unsigned)(unsigned short)Vpre[1][z] << 16);
      }
      __syncthreads();
    }

    int cur = 0;
    for (int kt = kstart; kt < kend; kt++) {
      const int kb = kt * 64;
      const unsigned short* ksc = Ks[cur];
      const unsigned int*   vtc = Vt2[cur];

      const int havenext = (kt + 1 < kend);
      if (havenext) {
#pragma unroll
        for (int it = 0; it < 3; it++) {
          Kpre[it] = *(const us8*)kptr[it];
          kptr[it] += kstep[it];
        }
        Vpre[0] = *(const us8*)vptr;
        Vpre[1] = *(const us8*)(vptr + NH * 256);
        vptr += 64 * NH * 256;
      }

      if (kb <= qwb + 31) {
        // S^T = K.Q^T (32x32x16): rows kpos, cols q=l31 (raw scores)
        f32x16 st2[2];
        __builtin_amdgcn_s_setprio(1);
#pragma unroll
        for (int mt = 0; mt < 2; mt++) {
          f32x16 acc;
#pragma unroll
          for (int j = 0; j < 16; j++) acc[j] = 0.0f;
#pragma unroll
          for (int s = 0; s < 12; s++) {
            bf16x8 kf = *(const bf16x8*)&ksc[(mt * 32 + l31) * KS + s * 16 + hh * 8];
            acc = __builtin_amdgcn_mfma_f32_32x32x16_bf16(kf, Qf[s], acc, 0, 0, 0);
          }
          st2[mt] = acc;
        }
        __builtin_amdgcn_s_setprio(0);

        // mask in RAW domain (diagonal tiles only)
        if (kb + 64 > qwb) {
#pragma unroll
          for (int mt = 0; mt < 2; mt++)
#pragma unroll
            for (int r = 0; r < 16; r++) {
              int kpos = kb + mt * 32 + (r & 3) + 8 * (r >> 2) + 4 * hh;
              st2[mt][r] = (kpos > qg) ? -1e30f : st2[mt][r];
            }
        }
        // tree max over 32 raw values (depth 5, max3-fusable)
        float t16[16];
#pragma unroll
        for (int r = 0; r < 16; r++) t16[r] = fmaxf(st2[0][r], st2[1][r]);
#pragma unroll
        for (int sw = 8; sw >= 1; sw >>= 1)
#pragma unroll
          for (int r = 0; r < 8; r++)
            if (r < sw) t16[r] = fmaxf(t16[r], t16[r + sw]);
        float mloc = t16[0] * qs2;   // qs2 > 0: max commutes with scale
        mloc = fmaxf(mloc, __shfl_xor(mloc, 32, 64));
        // defer-max (T13)
        if (!__all(mloc <= m_i + 8.0f)) {
          float m_new = fmaxf(m_i, mloc);
          float alpha = exp2f(m_i - m_new);
          l_i *= alpha;
#pragma unroll
          for (int mt = 0; mt < 4; mt++)
#pragma unroll
            for (int j = 0; j < 16; j++) O2[mt][j] *= alpha;
          m_i = m_new;
        }
        // p = exp2(fma(raw, qs2, -m_i)); tree-sum
        const float nm = -m_i;
#pragma unroll
        for (int mt = 0; mt < 2; mt++)
#pragma unroll
          for (int r = 0; r < 16; r++) {
            float p = exp2f(fmaf(st2[mt][r], qs2, nm));
            st2[mt][r] = p;
          }
        float s16[16];
#pragma unroll
        for (int r = 0; r < 16; r++) s16[r] = st2[0][r] + st2[1][r];
#pragma unroll
        for (int sw = 8; sw >= 1; sw >>= 1)
#pragma unroll
          for (int r = 0; r < 8; r++)
            if (r < sw) s16[r] += s16[r + sw];
        float psum = s16[0];
        psum += __shfl_xor(psum, 32, 64);
        l_i += psum;

        // P -> PV B-frags; cross-half exchange via shfl_xor(32)
        bf16x8 pf[4];
#pragma unroll
        for (int ss = 0; ss < 4; ss++) {
          const int pmt = ss >> 1, gg = ss & 1;
          unsigned int U0 = pack2bf(st2[pmt][gg * 8 + 0], st2[pmt][gg * 8 + 1]);
          unsigned int U1 = pack2bf(st2[pmt][gg * 8 + 2], st2[pmt][gg * 8 + 3]);
          unsigned int U2 = pack2bf(st2[pmt][gg * 8 + 4], st2[pmt][gg * 8 + 5]);
          unsigned int U3 = pack2bf(st2[pmt][gg * 8 + 6], st2[pmt][gg * 8 + 7]);
          unsigned int E0 = __shfl_xor(hh ? U0 : U2, 32, 64);
          unsigned int E1 = __shfl_xor(hh ? U1 : U3, 32, 64);
          ui4 pd;
          pd.x = hh ? E0 : U0;
          pd.y = hh ? E1 : U1;
          pd.z = hh ? U2 : E0;
          pd.w = hh ? U3 : E1;
          pf[ss] = __builtin_bit_cast(bf16x8, pd);
        }

        // PV as O^T = V^T.P^T
        __builtin_amdgcn_s_setprio(1);
#pragma unroll
        for (int ss = 0; ss < 4; ss++) {
#pragma unroll
          for (int mt = 0; mt < 4; mt++) {
            int v = mt * 32 + l31;
            const unsigned int* vp =
                &vtc[v * VS + ((ss * 8 + hh * 4) ^ (((v >> 3) & 7) << 2))];
            bf16x8 bv = *(const bf16x8*)vp;
            O2[mt] = __builtin_amdgcn_mfma_f32_32x32x16_bf16(bv, pf[ss], O2[mt],
                                                             0, 0, 0);
          }
        }
        __builtin_amdgcn_s_setprio(0);
      }

      if (havenext) {
#pragma unroll
        for (int it = 0; it < 3; it++)
          *(us8*)&Ks[cur ^ 1][kr_[it] * KS + kc_[it] * 8] = Kpre[it];
#pragma unroll
        for (int z = 0; z < 8; z++) {
          int d = m16 * 8 + z;
          Vt2[cur ^ 1][d * VS + (hp ^ vkey)] =
              (unsigned)(unsigned short)Vpre[0][z] |
              ((unsigned)(unsigned short)Vpre[1][z] << 16);
        }
        __syncthreads();
        cur ^= 1;
      }
    }

    // ---- partial epilogue ----
    unsigned short* op = item ? op1 : op0;
    float* mlp = item ? mlp1 : mlp0;
    const size_t basep = (size_t)(b * S_LEN + qg) * NH + h;
    unsigned short* orow = op + basep * 128;
#pragma unroll
    for (int mt = 0; mt < 4; mt++) {
#pragma unroll
      for (int g = 0; g < 4; g++) {
        us4 pk;
#pragma unroll
        for (int j = 0; j < 4; j++) pk[j] = f2bf(O2[mt][g * 4 + j]);
        *(us4*)(orow + mt * 32 + g * 8 + hh * 4) = pk;
      }
    }
    if (hh == 0) {
      mlp[basep * 2 + 0] = m_i;
      mlp[basep * 2 + 1] = l_i;
    }
  }
}

// ---------------- combine the two K-halves per q-row ---------------------------
__global__ __launch_bounds__(256) void attn_combine_kernel(
    const unsigned short* __restrict__ op0, const unsigned short* __restrict__ op1,
    const float* __restrict__ mlp0, const float* __restrict__ mlp1,
    __hip_bfloat16* __restrict__ attn_out) {
  const int bs = blockIdx.x;
  const int tid = threadIdx.x;
  const int h = tid >> 4, dc = (tid & 15) * 8;
  const size_t basep = (size_t)bs * NH + h;
  const us8 a = *(const us8*)(op0 + basep * 128 + dc);
  const us8 c = *(const us8*)(op1 + basep * 128 + dc);
  const float m0 = mlp0[basep * 2], l0 = mlp0[basep * 2 + 1];
  const float m1 = mlp1[basep * 2], l1 = mlp1[basep * 2 + 1];
  const float m = fmaxf(m0, m1);
  const float a0 = exp2f(m0 - m), a1 = exp2f(m1 - m);
  const float inv = 1.0f / (l0 * a0 + l1 * a1);
  us8 o;
#pragma unroll
  for (int z = 0; z < 8; z++) {
    float v = (bfu2f((unsigned short)a[z]) * a0 +
               bfu2f((unsigned short)c[z]) * a1) * inv;
    o[z] = f2bf(v);
  }
  *(us8*)((unsigned short*)attn_out + (size_t)bs * (NH * DV) + h * DV + dc) = o;
}

// ---------------- launch ----------------
extern "C" void kernel_launch(void* const* d_in, const int* in_sizes, int n_in,
                              void* d_out, int out_size, void* d_ws, size_t ws_size,
                              hipStream_t stream) {
  const float* x     = (const float*)d_in[0];
  const float* freqs = (const float*)d_in[2];
  const float* wq    = (const float*)d_in[4];
  const float* wkva  = (const float*)d_in[5];
  const float* wkvb  = (const float*)d_in[6];
  const float* wo    = (const float*)d_in[7];
  const float* kvnw  = (const float*)d_in[8];
  float* out = (float*)d_out;

  char* ws = (char*)d_ws;
  size_t off = 0;
  auto alloc = [&](size_t bytes) {
    void* p = ws + off;
    off += (bytes + 255) & ~(size_t)255;
    return p;
  };
  __hip_bfloat16* x_bf    = (__hip_bfloat16*)alloc((size_t)BS_TOT * 2048 * 2);
  __hip_bfloat16* wq_bf   = (__hip_bfloat16*)alloc((size_t)3072 * 2048 * 2);
  __hip_bfloat16* wkva_bf = (__hip_bfloat16*)alloc((size_t)768 * 2048 * 2);  // contiguous with wq_bf -> 3840 rows
  __hip_bfloat16* wkvb_bf = (__hip_bfloat16*)alloc((size_t)4096 * 512 * 2);
  __hip_bfloat16* wo_bf   = (__hip_bfloat16*)alloc((size_t)2048 * 2048 * 2);
  __hip_bfloat16* qkv_bf  = (__hip_bfloat16*)alloc((size_t)BS_TOT * QSTR * 2);
  __hip_bfloat16* latent  = (__hip_bfloat16*)alloc((size_t)BS_TOT * 512 * 2);
  __hip_bfloat16* kpe     = (__hip_bfloat16*)alloc((size_t)BS_TOT * 64 * 2);
  __hip_bfloat16* kvup    = (__hip_bfloat16*)alloc((size_t)BS_TOT * 4096 * 2);
  __hip_bfloat16* attn    = (__hip_bfloat16*)alloc((size_t)BS_TOT * 2048 * 2);

  unsigned short* op0 = (unsigned short*)x_bf;
  unsigned short* op1 = (unsigned short*)wq_bf;
  float* mlp0 = (float*)latent;
  float* mlp1 = mlp0 + (size_t)BS_TOT * NH * 2;

  cast_all_kernel<<<2048, 256, 0, stream>>>(x, wq, wkva, wkvb, wo,
                                            x_bf, wq_bf, wkva_bf, wkvb_bf, wo_bf);

  gemm_bt256<1><<<dim3(240), 512, 0, stream>>>(
      x_bf, wq_bf, qkv_bf, BS_TOT, QSTR, 2048, QSTR / 256);
  rope_rms_kernel<<<BS_TOT, 256, 0, stream>>>(qkv_bf, kvnw, freqs, latent, kpe);

  gemm_bt256<1><<<dim3(256), 512, 0, stream>>>(
      latent, wkvb_bf, kvup, BS_TOT, 4096, 512, 16);

  attn_mfma_kernel<<<dim3(256, 1, 1), 512, 0, stream>>>(
      qkv_bf, kvup, kpe, op0, op1, mlp0, mlp1);
  attn_combine_kernel<<<dim3(BS_TOT, 1, 1), 256, 0, stream>>>(
      op0, op1, mlp0, mlp1, attn);

  gemm_bt256<0><<<dim3(128), 512, 0, stream>>>(
      attn, wo_bf, out, BS_TOT, 2048, 2048, 8);
}